// Round 18
// baseline (704.817 us; speedup 1.0000x reference)
//
#include <hip/hip_runtime.h>
#include <hip/hip_bf16.h>
#include <hip/hip_fp16.h>
#include <math.h>

constexpr int N_NODES = 50000;
constexpr int N_EDGES = 850000;
constexpr int HDIM = 128;   // H*D

typedef _Float16 h2v __attribute__((ext_vector_type(2)));

// ---------------- CSR build: two-phase bucket sort ----------------
constexpr int NB2 = 128;                                // buckets
constexpr int RANGE2 = (N_NODES + NB2 - 1) / NB2;       // 391 nodes/bucket
constexpr int CAP = 8192;                               // bucket capacity (avg 6641)
constexpr int CHUNK = 8192;                             // edges per phase-A block
constexpr int GA = (N_EDGES + CHUNK - 1) / CHUNK;       // 104 blocks

__global__ void k_partA(const int* __restrict__ src, const int* __restrict__ dst,
                        int* __restrict__ g_cursor, unsigned* __restrict__ bucket) {
    __shared__ int hist[NB2];
    int tid = threadIdx.x;
    int e0 = blockIdx.x * CHUNK;
    int e1 = min(e0 + CHUNK, N_EDGES);
    if (tid < NB2) hist[tid] = 0;
    __syncthreads();
    for (int i = e0 + tid; i < e1; i += 1024) {
        int d = dst[i];
        atomicAdd(&hist[d / RANGE2], 1);
    }
    __syncthreads();
    int base = 0;
    if (tid < NB2) base = atomicAdd(&g_cursor[tid], hist[tid]);
    __syncthreads();
    if (tid < NB2) hist[tid] = base;
    __syncthreads();
    for (int i = e0 + tid; i < e1; i += 1024) {
        int d = dst[i];
        int s = src[i];
        int b = d / RANGE2;
        int p = atomicAdd(&hist[b], 1);
        bucket[b * CAP + p] = (unsigned)s | ((unsigned)(d - b * RANGE2) << 16);
    }
}

__global__ void k_partB(const unsigned* __restrict__ bucket, const int* __restrict__ cnts,
                        int* __restrict__ rowstart, int* __restrict__ esrc,
                        int* __restrict__ dbin) {
    __shared__ int cnt_s[NB2];
    __shared__ int hist[RANGE2];
    __shared__ int lcur[RANGE2];
    __shared__ int wsum[7];
    int b = blockIdx.x, tid = threadIdx.x;
    int lo = b * RANGE2;
    int myCount = cnts[b];
    if (tid < NB2) cnt_s[tid] = cnts[tid];
    __syncthreads();
    for (int off = 1; off < NB2; off <<= 1) {
        int t = (tid < NB2 && tid >= off) ? cnt_s[tid - off] : 0;
        __syncthreads();
        if (tid < NB2) cnt_s[tid] += t;
        __syncthreads();
    }
    int base = cnt_s[b] - myCount;
    for (int j = tid; j < RANGE2; j += 1024) hist[j] = 0;
    __syncthreads();
    const unsigned* my = bucket + (size_t)b * CAP;
    for (int i = tid; i < myCount; i += 1024) atomicAdd(&hist[my[i] >> 16], 1);
    __syncthreads();
    int v = 0;
    if (tid < 448) v = (tid < RANGE2) ? hist[tid] : 0;
    int inc = v;
    int lane = tid & 63;
#pragma unroll
    for (int off = 1; off < 64; off <<= 1) {
        int t = __shfl_up(inc, off, 64);
        if (lane >= off) inc += t;
    }
    if (tid < 448 && lane == 63) wsum[tid >> 6] = inc;
    __syncthreads();
    if (tid < RANGE2) {
        int woff = 0;
        for (int w = 0; w < (tid >> 6); w++) woff += wsum[w];
        int excl = woff + inc - v;
        lcur[tid] = excl;
        int node = lo + tid;
        if (node < N_NODES) {
            rowstart[node] = base + excl;
            atomicAdd(&dbin[min(v, 255)], 1);   // degree histogram for perm build
        }
    }
    if (b == 0 && tid == 0) rowstart[N_NODES] = N_EDGES;
    __syncthreads();
    for (int i = tid; i < myCount; i += 1024) {
        unsigned p = my[i];
        int pos = atomicAdd(&lcur[p >> 16], 1);
        esrc[base + pos] = (int)(p & 0xFFFFu);
    }
}

// ---------------- degree-perm: scan bins, then scatter node ids by degree ----------------
__global__ void k_dperm(int* __restrict__ dbin) {
    __shared__ int sm[256];
    int tid = threadIdx.x;  // 256
    int v = dbin[tid];
    sm[tid] = v;
    __syncthreads();
    // serial-ish scan (256 elems, trivial cost)
    if (tid == 0) {
        int run = 0;
        for (int i = 0; i < 256; i++) { int t = sm[i]; sm[i] = run; run += t; }
    }
    __syncthreads();
    dbin[tid] = sm[tid];   // now exclusive base / cursor
}

__global__ void k_dscatter(const int* __restrict__ rowstart, int* __restrict__ dbin,
                           int* __restrict__ perm) {
    int n = blockIdx.x * 1024 + threadIdx.x;
    if (n >= N_NODES) return;
    int deg = rowstart[n + 1] - rowstart[n];
    int pos = atomicAdd(&dbin[min(deg, 255)], 1);
    perm[pos] = n;
}

// ---------------- W pre-pack + cursor zeroing ----------------
__global__ void k_wpack(const float* __restrict__ W0, const float* __restrict__ W1,
                        const float* __restrict__ W2, h2v* __restrict__ wpk,
                        int* __restrict__ g_cursor, int* __restrict__ dbin) {
    int gid = blockIdx.x * 256 + threadIdx.x;  // 3 * 8192
    if (blockIdx.x == 0) {
        if (threadIdx.x < NB2) g_cursor[threadIdx.x] = 0;
        dbin[threadIdx.x] = 0;
    }
    if (gid >= 3 * 8192) return;
    int L = gid >> 13, r = gid & 8191;
    int k2 = r >> 7, c = r & 127;
    const float* W = (L == 0) ? W0 : ((L == 1) ? W1 : W2);
    h2v v;
    v.x = (_Float16)W[(2 * k2) * HDIM + c];
    v.y = (_Float16)W[(2 * k2 + 1) * HDIM + c];
    wpk[gid] = v;
}

// ---------------- GEMM v3 (fdot2, W from L2): feat(fp16) = act(in) @ W + fused el/er ----------------
__global__ void k_gemm3(const __half* __restrict__ h, const int* __restrict__ xidx,
                        const float* __restrict__ embed, const float4* __restrict__ wpk4,
                        __half* __restrict__ feat_h, const float* __restrict__ bnsc,
                        const float* __restrict__ bnsh, const float* __restrict__ al,
                        const float* __restrict__ ar, float* __restrict__ el,
                        float* __restrict__ er, int mode) {
    __shared__ h2v hsT2[64 * 68];    // [k2][node(+4 pad)] = 17.4 KB
    int tid = threadIdx.x;
    int nbase = blockIdx.x * 64;
    {
        int r = tid & 63, cg = tid >> 6;
        int n = nbase + r;
        bool ok = n < N_NODES;
        h2v vals[16];
#pragma unroll
        for (int j = 0; j < 16; j++) { vals[j].x = (_Float16)0.f; vals[j].y = (_Float16)0.f; }
        if (ok) {
            if (mode == 0) {
                int xi = xidx[n];
                const float4* ep = reinterpret_cast<const float4*>(&embed[xi * HDIM + cg * 32]);
#pragma unroll
                for (int q = 0; q < 8; q++) {
                    float4 e = ep[q];
                    vals[2 * q].x = (_Float16)e.x; vals[2 * q].y = (_Float16)e.y;
                    vals[2 * q + 1].x = (_Float16)e.z; vals[2 * q + 1].y = (_Float16)e.w;
                }
            } else {
                const float4* hp = reinterpret_cast<const float4*>(&h[(size_t)n * HDIM + cg * 32]);
#pragma unroll
                for (int q = 0; q < 4; q++) {
                    float4 raw = hp[q];
                    __half2 us[4] = {*(__half2*)&raw.x, *(__half2*)&raw.y,
                                     *(__half2*)&raw.z, *(__half2*)&raw.w};
#pragma unroll
                    for (int t2 = 0; t2 < 4; t2++) {
                        int j = q * 4 + t2;
                        int c2g = cg * 16 + j;
                        float2 sc = *reinterpret_cast<const float2*>(&bnsc[2 * c2g]);
                        float2 sh = *reinterpret_cast<const float2*>(&bnsh[2 * c2g]);
                        float v0 = __half2float(__low2half(us[t2])) * sc.x + sh.x;
                        float v1 = __half2float(__high2half(us[t2])) * sc.y + sh.y;
                        v0 = (v0 > 0.f) ? v0 : expm1f(v0);
                        v1 = (v1 > 0.f) ? v1 : expm1f(v1);
                        vals[j].x = (_Float16)v0; vals[j].y = (_Float16)v1;
                    }
                }
            }
        }
#pragma unroll
        for (int j = 0; j < 16; j++) hsT2[(cg * 16 + j) * 68 + r] = vals[j];
    }
    __syncthreads();
    int c4 = (tid & 31) * 4;
    int n8 = (tid >> 5) * 8;
    int wlane = tid & 31;
    float acc[8][4] = {};
#pragma unroll 4
    for (int k2 = 0; k2 < 64; k2++) {
        float4 wf = wpk4[k2 * 32 + wlane];   // L2-resident W row chunk
        float4 a0 = *reinterpret_cast<const float4*>(&hsT2[k2 * 68 + n8]);
        float4 a1 = *reinterpret_cast<const float4*>(&hsT2[k2 * 68 + n8 + 4]);
        h2v w[4] = {*(h2v*)&wf.x, *(h2v*)&wf.y, *(h2v*)&wf.z, *(h2v*)&wf.w};
        h2v av[8] = {*(h2v*)&a0.x, *(h2v*)&a0.y, *(h2v*)&a0.z, *(h2v*)&a0.w,
                     *(h2v*)&a1.x, *(h2v*)&a1.y, *(h2v*)&a1.z, *(h2v*)&a1.w};
#pragma unroll
        for (int i = 0; i < 8; i++)
#pragma unroll
            for (int j = 0; j < 4; j++)
                acc[i][j] = __builtin_amdgcn_fdot2(av[i], w[j], acc[i][j], false);
    }
#pragma unroll
    for (int i = 0; i < 8; i++) {
        int n = nbase + n8 + i;
        if (n < N_NODES) {
            __half2* p = reinterpret_cast<__half2*>(&feat_h[(size_t)n * HDIM + c4]);
            p[0] = __floats2half2_rn(acc[i][0], acc[i][1]);
            p[1] = __floats2half2_rn(acc[i][2], acc[i][3]);
        }
    }
    float4 alv = *reinterpret_cast<const float4*>(&al[c4]);
    float4 arv = *reinterpret_cast<const float4*>(&ar[c4]);
    float pl[8], pr[8];
#pragma unroll
    for (int i = 0; i < 8; i++) {
        pl[i] = acc[i][0] * alv.x + acc[i][1] * alv.y + acc[i][2] * alv.z + acc[i][3] * alv.w;
        pr[i] = acc[i][0] * arv.x + acc[i][1] * arv.y + acc[i][2] * arv.z + acc[i][3] * arv.w;
    }
#pragma unroll
    for (int off = 1; off < 8; off <<= 1)
#pragma unroll
        for (int i = 0; i < 8; i++) {
            pl[i] += __shfl_xor(pl[i], off, 64);
            pr[i] += __shfl_xor(pr[i], off, 64);
        }
    int lane = tid & 63;
    if ((lane & 7) == 0) {
        int head = c4 >> 5;
#pragma unroll
        for (int i = 0; i < 8; i++) {
            int n = nbase + n8 + i;
            if (n < N_NODES) {
                el[n * 4 + head] = pl[i];
                er[n * 4 + head] = pr[i];
            }
        }
    }
}

// ---------------- aggregation v8: agg7 + degree-perm node assignment ----------------
__global__ void k_agg8(const __half* __restrict__ feat_h, const float* __restrict__ el,
                       const float* __restrict__ er, const int* __restrict__ rowstart,
                       const int* __restrict__ esrc, const float* __restrict__ snorm_n,
                       __half* __restrict__ h, const float* __restrict__ bnsc,
                       const float* __restrict__ bnsh, const int* __restrict__ perm,
                       int layer) {
    __shared__ __align__(16) int2 lds[4][2][2][32][4];  // [wave][h2][buf][slot][head], 16 KB
    int tid = threadIdx.x;
    int wave = tid >> 6, lane = tid & 63;
    int h2 = lane >> 5, hl = lane & 31;
    int dp = hl & 15, epair = hl >> 4, head = dp >> 2;
    int n = perm[blockIdx.x * 8 + wave * 2 + h2];   // degree-sorted assignment
    int e0 = rowstart[n];
    int deg = rowstart[n + 1] - e0;           // >= 1 (self loops)
    int dmax = max(deg, __shfl_xor(deg, 32, 64));
    float4 er4 = *(const float4*)&er[n * 4];
    const float4* fp = reinterpret_cast<const float4*>(feat_h);
    float s = 0.f;
    float a[8] = {};
    int nch = (dmax + 31) >> 5;

    int idx0 = e0 + min(hl, deg - 1);
    int sidx_p = esrc[idx0];
    float4 el_p = *(const float4*)&el[sidx_p * 4];
    bool val_p = hl < deg;

    for (int c = 0; c < nch; c++) {
        float w0 = 0.f, w1 = 0.f, w2 = 0.f, w3 = 0.f;
        int sv = sidx_p;
        if (val_p) {
            float ex = el_p.x + er4.x, ey = el_p.y + er4.y;
            float ez = el_p.z + er4.z, ew = el_p.w + er4.w;
            ex = fmaxf(ex, 0.f) + 0.2f * fminf(ex, 0.f);
            ey = fmaxf(ey, 0.f) + 0.2f * fminf(ey, 0.f);
            ez = fmaxf(ez, 0.f) + 0.2f * fminf(ez, 0.f);
            ew = fmaxf(ew, 0.f) + 0.2f * fminf(ew, 0.f);
            w0 = __expf(ex); w1 = __expf(ey); w2 = __expf(ez); w3 = __expf(ew);
        }
        int4* wp = reinterpret_cast<int4*>(&lds[wave][h2][c & 1][hl][0]);
        wp[0] = make_int4(sv, __float_as_int(w0), sv, __float_as_int(w1));
        wp[1] = make_int4(sv, __float_as_int(w2), sv, __float_as_int(w3));
        if (c + 1 < nch) {
            int slot = (c + 1) * 32 + hl;
            int idx = e0 + min(slot, deg - 1);
            sidx_p = esrc[idx];
            el_p = *(const float4*)&el[sidx_p * 4];
            val_p = slot < deg;
        }
        int cnt = min(32, dmax - c * 32);
        int iters = (cnt + 1) >> 1;
#pragma unroll 4
        for (int j = 0; j < iters; j++) {
            int2 rec = lds[wave][h2][c & 1][j * 2 + epair][head];
            float w = __int_as_float(rec.y);
            float4 fv = fp[(size_t)rec.x * 16 + dp];
            __half2 p0 = *(__half2*)&fv.x, p1 = *(__half2*)&fv.y;
            __half2 p2 = *(__half2*)&fv.z, p3 = *(__half2*)&fv.w;
            a[0] = fmaf(__half2float(__low2half(p0)), w, a[0]);
            a[1] = fmaf(__half2float(__high2half(p0)), w, a[1]);
            a[2] = fmaf(__half2float(__low2half(p1)), w, a[2]);
            a[3] = fmaf(__half2float(__high2half(p1)), w, a[3]);
            a[4] = fmaf(__half2float(__low2half(p2)), w, a[4]);
            a[5] = fmaf(__half2float(__high2half(p2)), w, a[5]);
            a[6] = fmaf(__half2float(__low2half(p3)), w, a[6]);
            a[7] = fmaf(__half2float(__high2half(p3)), w, a[7]);
            s += w;
        }
    }
#pragma unroll
    for (int k = 0; k < 8; k++) a[k] += __shfl_xor(a[k], 16, 64);
    s += __shfl_xor(s, 16, 64);
    if (epair == 0) {
        float inv = 1.f / s;
        int d0 = dp * 8;
        float r[8];
#pragma unroll
        for (int k = 0; k < 8; k++) r[k] = a[k] * inv;
        if (layer > 0) {
            float4 hraw = *reinterpret_cast<const float4*>(&h[(size_t)n * HDIM + d0]);
            __half2 q0 = *(__half2*)&hraw.x, q1 = *(__half2*)&hraw.y;
            __half2 q2 = *(__half2*)&hraw.z, q3 = *(__half2*)&hraw.w;
            float hv[8] = {__half2float(__low2half(q0)), __half2float(__high2half(q0)),
                           __half2float(__low2half(q1)), __half2float(__high2half(q1)),
                           __half2float(__low2half(q2)), __half2float(__high2half(q2)),
                           __half2float(__low2half(q3)), __half2float(__high2half(q3))};
            float4 sc0 = *reinterpret_cast<const float4*>(&bnsc[d0]);
            float4 sc1 = *reinterpret_cast<const float4*>(&bnsc[d0 + 4]);
            float4 sh0 = *reinterpret_cast<const float4*>(&bnsh[d0]);
            float4 sh1 = *reinterpret_cast<const float4*>(&bnsh[d0 + 4]);
            float scv[8] = {sc0.x, sc0.y, sc0.z, sc0.w, sc1.x, sc1.y, sc1.z, sc1.w};
            float shv[8] = {sh0.x, sh0.y, sh0.z, sh0.w, sh1.x, sh1.y, sh1.z, sh1.w};
#pragma unroll
            for (int k = 0; k < 8; k++) {
                float t = hv[k] * scv[k] + shv[k];
                t = (t > 0.f) ? t : expm1f(t);
                r[k] += t;
                r[k] = (r[k] > 0.f) ? r[k] : expm1f(r[k]);
            }
        }
        float sn = snorm_n[n];
#pragma unroll
        for (int k = 0; k < 8; k++) r[k] *= sn;
        float4 outv;
        *(__half2*)&outv.x = __floats2half2_rn(r[0], r[1]);
        *(__half2*)&outv.y = __floats2half2_rn(r[2], r[3]);
        *(__half2*)&outv.z = __floats2half2_rn(r[4], r[5]);
        *(__half2*)&outv.w = __floats2half2_rn(r[6], r[7]);
        *reinterpret_cast<float4*>(&h[(size_t)n * HDIM + d0]) = outv;
    }
}

// ---------------- BatchNorm: deterministic two-level fp32 reduction (h fp16) ----------------
constexpr int BN_NB = 200;
constexpr int BN_ROWS = N_NODES / BN_NB;  // 250

__global__ void k_bn1(const __half* __restrict__ h, float* __restrict__ part) {
    __shared__ float red[8][128][2];
    int tid = threadIdx.x;
    int c = tid & 127, g = tid >> 7;
    int r0 = blockIdx.x * BN_ROWS;
    float s = 0.f, s2 = 0.f;
    for (int r = r0 + g; r < r0 + BN_ROWS; r += 8) {
        float x = __half2float(h[(size_t)r * HDIM + c]);
        s += x;
        s2 = fmaf(x, x, s2);
    }
    red[g][c][0] = s;
    red[g][c][1] = s2;
    __syncthreads();
    if (tid < 128) {
        float ts = 0.f, ts2 = 0.f;
#pragma unroll
        for (int g2 = 0; g2 < 8; g2++) { ts += red[g2][tid][0]; ts2 += red[g2][tid][1]; }
        part[blockIdx.x * 256 + tid] = ts;
        part[blockIdx.x * 256 + 128 + tid] = ts2;
    }
}

__global__ void k_bn2(const float* __restrict__ part, const float* __restrict__ gamma,
                      const float* __restrict__ beta, float* __restrict__ scale,
                      float* __restrict__ shift) {
    int c = threadIdx.x;  // 128
    float s = 0.f, s2 = 0.f;
    for (int b = 0; b < BN_NB; b++) {
        s += part[b * 256 + c];
        s2 += part[b * 256 + 128 + c];
    }
    float mu = s / N_NODES;
    float var = s2 / N_NODES - mu * mu;
    float sc = gamma[c] * rsqrtf(var + 1e-5f);
    scale[c] = sc;
    shift[c] = beta[c] - mu * sc;
}

// ---------------- classifier (h fp16) ----------------
__global__ void k_classifier(const __half* __restrict__ h, const float* __restrict__ W1,
                             const float* __restrict__ b1, const float* __restrict__ W2,
                             const float* __restrict__ b2, const float* __restrict__ bnsc,
                             const float* __restrict__ bnsh, float* __restrict__ out) {
    __shared__ float hs[16][128];
    int tid = threadIdx.x;
    int nbase = blockIdx.x * 16;
    for (int i = tid; i < 16 * 128; i += 256) {
        int r = i >> 7, c = i & 127;
        int n = nbase + r;
        float v = 0.f;
        if (n < N_NODES) {
            v = __half2float(h[(size_t)n * HDIM + c]) * bnsc[c] + bnsh[c];
            v = (v > 0.f) ? v : expm1f(v);
        }
        hs[r][c] = v;
    }
    __syncthreads();
    int j = tid & 63;
    int g = tid >> 6;
    float bj = b1[j];
    float acc[4] = {bj, bj, bj, bj};
    for (int k = 0; k < 128; k++) {
        float w = W1[k * 64 + j];
#pragma unroll
        for (int i = 0; i < 4; i++) acc[i] += hs[g * 4 + i][k] * w;
    }
    float w20 = W2[j * 2], w21 = W2[j * 2 + 1];
    float res[8];
#pragma unroll
    for (int i = 0; i < 4; i++) {
        float hid = fmaxf(acc[i], 0.f);
        res[2 * i] = hid * w20;
        res[2 * i + 1] = hid * w21;
    }
#pragma unroll
    for (int off = 1; off < 64; off <<= 1)
#pragma unroll
        for (int i = 0; i < 8; i++) res[i] += __shfl_xor(res[i], off, 64);
    if (j < 8) {
        int n = nbase + g * 4 + (j >> 1);
        if (n < N_NODES) out[n * 2 + (j & 1)] = res[j] + b2[j & 1];
    }
}

// ----------------------------------------------------------------
extern "C" void kernel_launch(void* const* d_in, const int* in_sizes, int n_in,
                              void* d_out, int out_size, void* d_ws, size_t ws_size,
                              hipStream_t stream) {
    const int* x = (const int*)d_in[0];
    const int* src = (const int*)d_in[1];
    const int* dst = (const int*)d_in[2];
    const float* snorm_n = (const float*)d_in[3];
    const float* embed = (const float*)d_in[5];
    const float* Ws[3] = {(const float*)d_in[6], (const float*)d_in[11], (const float*)d_in[16]};
    const float* als[3] = {(const float*)d_in[7], (const float*)d_in[12], (const float*)d_in[17]};
    const float* ars[3] = {(const float*)d_in[8], (const float*)d_in[13], (const float*)d_in[18]};
    const float* gms[3] = {(const float*)d_in[9], (const float*)d_in[14], (const float*)d_in[19]};
    const float* bts[3] = {(const float*)d_in[10], (const float*)d_in[15], (const float*)d_in[20]};
    const float* cls1_w = (const float*)d_in[21];
    const float* cls1_b = (const float*)d_in[22];
    const float* cls2_w = (const float*)d_in[23];
    const float* cls2_b = (const float*)d_in[24];
    float* out = (float*)d_out;

    char* ws = (char*)d_ws;
    size_t off = 0;
    auto alloc = [&](size_t bytes) {
        void* p = ws + off;
        off = (off + bytes + 255) & ~(size_t)255;
        return p;
    };
    __half* h = (__half*)alloc((size_t)N_NODES * HDIM * 2);
    __half* feat_h = (__half*)alloc((size_t)N_NODES * HDIM * 2);
    float* el = (float*)alloc((size_t)N_NODES * 4 * 4);
    float* er = (float*)alloc((size_t)N_NODES * 4 * 4);
    int* rowstart = (int*)alloc((size_t)(N_NODES + 1) * 4);
    int* esrc = (int*)alloc((size_t)N_EDGES * 4);
    int* perm = (int*)alloc((size_t)N_NODES * 4);
    int* g_cursor = (int*)alloc((size_t)NB2 * 4);
    int* dbin = (int*)alloc(256 * 4);
    float* bn_part = (float*)alloc((size_t)BN_NB * 256 * 4);
    float* bn_scale = (float*)alloc(128 * 4);
    float* bn_shift = (float*)alloc(128 * 4);
    h2v* wpk = (h2v*)alloc((size_t)3 * 8192 * 4);
    unsigned* g_bucket = (unsigned*)feat_h;  // 4 MB alias; CSR build finishes before gemm
    (void)ws_size; (void)in_sizes; (void)n_in; (void)out_size;

    // wpack also zeroes g_cursor + dbin (runs before partA in the serial stream)
    k_wpack<<<(3 * 8192 + 255) / 256, 256, 0, stream>>>(Ws[0], Ws[1], Ws[2], wpk,
                                                        g_cursor, dbin);
    k_partA<<<GA, 1024, 0, stream>>>(src, dst, g_cursor, g_bucket);
    k_partB<<<NB2, 1024, 0, stream>>>(g_bucket, g_cursor, rowstart, esrc, dbin);
    k_dperm<<<1, 256, 0, stream>>>(dbin);
    k_dscatter<<<(N_NODES + 1023) / 1024, 1024, 0, stream>>>(rowstart, dbin, perm);

    for (int L = 0; L < 3; L++) {
        const float4* wpk4 = reinterpret_cast<const float4*>(wpk + (size_t)L * 8192);
        k_gemm3<<<(N_NODES + 63) / 64, 256, 0, stream>>>(h, x, embed, wpk4,
                                                         feat_h, bn_scale, bn_shift,
                                                         als[L], ars[L], el, er, L == 0 ? 0 : 1);
        k_agg8<<<N_NODES / 8, 256, 0, stream>>>(feat_h, el, er, rowstart, esrc,
                                                snorm_n, h, bn_scale, bn_shift, perm, L);
        k_bn1<<<BN_NB, 1024, 0, stream>>>(h, bn_part);
        k_bn2<<<1, 128, 0, stream>>>(bn_part, gms[L], bts[L], bn_scale, bn_shift);
    }

    k_classifier<<<(N_NODES + 15) / 16, 256, 0, stream>>>(h, cls1_w, cls1_b, cls2_w, cls2_b,
                                                          bn_scale, bn_shift, out);
}

// Round 19
// 432.196 us; speedup vs baseline: 1.6308x; 1.6308x over previous
//
#include <hip/hip_runtime.h>
#include <hip/hip_bf16.h>
#include <hip/hip_fp16.h>
#include <math.h>

constexpr int N_NODES = 50000;
constexpr int N_EDGES = 850000;
constexpr int HDIM = 128;   // H*D

typedef _Float16 h2v __attribute__((ext_vector_type(2)));

// ---------------- CSR build: two-phase bucket sort ----------------
constexpr int NB2 = 128;                                // buckets
constexpr int RANGE2 = (N_NODES + NB2 - 1) / NB2;       // 391 nodes/bucket
constexpr int CAP = 8192;                               // bucket capacity (avg 6641)
constexpr int CHUNK = 8192;                             // edges per phase-A block
constexpr int GA = (N_EDGES + CHUNK - 1) / CHUNK;       // 104 blocks

__global__ void k_partA(const int* __restrict__ src, const int* __restrict__ dst,
                        int* __restrict__ g_cursor, unsigned* __restrict__ bucket) {
    __shared__ int hist[NB2];
    int tid = threadIdx.x;
    int e0 = blockIdx.x * CHUNK;
    int e1 = min(e0 + CHUNK, N_EDGES);
    if (tid < NB2) hist[tid] = 0;
    __syncthreads();
    for (int i = e0 + tid; i < e1; i += 1024) {
        int d = dst[i];
        atomicAdd(&hist[d / RANGE2], 1);
    }
    __syncthreads();
    int base = 0;
    if (tid < NB2) base = atomicAdd(&g_cursor[tid], hist[tid]);
    __syncthreads();
    if (tid < NB2) hist[tid] = base;
    __syncthreads();
    for (int i = e0 + tid; i < e1; i += 1024) {
        int d = dst[i];
        int s = src[i];
        int b = d / RANGE2;
        int p = atomicAdd(&hist[b], 1);
        bucket[b * CAP + p] = (unsigned)s | ((unsigned)(d - b * RANGE2) << 16);
    }
}

__global__ void k_partB(const unsigned* __restrict__ bucket, const int* __restrict__ cnts,
                        int* __restrict__ rowstart, int* __restrict__ esrc) {
    __shared__ int cnt_s[NB2];
    __shared__ int hist[RANGE2];
    __shared__ int lcur[RANGE2];
    __shared__ int wsum[7];
    int b = blockIdx.x, tid = threadIdx.x;
    int lo = b * RANGE2;
    int myCount = cnts[b];
    if (tid < NB2) cnt_s[tid] = cnts[tid];
    __syncthreads();
    for (int off = 1; off < NB2; off <<= 1) {
        int t = (tid < NB2 && tid >= off) ? cnt_s[tid - off] : 0;
        __syncthreads();
        if (tid < NB2) cnt_s[tid] += t;
        __syncthreads();
    }
    int base = cnt_s[b] - myCount;
    for (int j = tid; j < RANGE2; j += 1024) hist[j] = 0;
    __syncthreads();
    const unsigned* my = bucket + (size_t)b * CAP;
    for (int i = tid; i < myCount; i += 1024) atomicAdd(&hist[my[i] >> 16], 1);
    __syncthreads();
    int v = 0;
    if (tid < 448) v = (tid < RANGE2) ? hist[tid] : 0;
    int inc = v;
    int lane = tid & 63;
#pragma unroll
    for (int off = 1; off < 64; off <<= 1) {
        int t = __shfl_up(inc, off, 64);
        if (lane >= off) inc += t;
    }
    if (tid < 448 && lane == 63) wsum[tid >> 6] = inc;
    __syncthreads();
    if (tid < RANGE2) {
        int woff = 0;
        for (int w = 0; w < (tid >> 6); w++) woff += wsum[w];
        int excl = woff + inc - v;
        lcur[tid] = excl;
        int node = lo + tid;
        if (node < N_NODES) rowstart[node] = base + excl;
    }
    if (b == 0 && tid == 0) rowstart[N_NODES] = N_EDGES;
    __syncthreads();
    for (int i = tid; i < myCount; i += 1024) {
        unsigned p = my[i];
        int pos = atomicAdd(&lcur[p >> 16], 1);
        esrc[base + pos] = (int)(p & 0xFFFFu);
    }
}

// ---------------- degree-perm: per-block LDS histograms (no hot global atomics) ----------------
constexpr int DP_NB = (N_NODES + 1023) / 1024;  // 49 blocks

__global__ void k_dhist(const int* __restrict__ rowstart, int* __restrict__ g_bin,
                        int* __restrict__ bbase) {
    __shared__ int lh[256];
    int tid = threadIdx.x, b = blockIdx.x;
    if (tid < 256) lh[tid] = 0;
    __syncthreads();
    int n = b * 1024 + tid;
    if (n < N_NODES) {
        int deg = rowstart[n + 1] - rowstart[n];
        atomicAdd(&lh[min(deg, 255)], 1);
    }
    __syncthreads();
    if (tid < 256) bbase[b * 256 + tid] = atomicAdd(&g_bin[tid], lh[tid]);
}

__global__ void k_dscan(int* __restrict__ g_bin) {
    // single wave sufficient; serial scan of 256 ints
    if (threadIdx.x == 0) {
        int run = 0;
        for (int i = 0; i < 256; i++) { int t = g_bin[i]; g_bin[i] = run; run += t; }
    }
}

__global__ void k_dscatter2(const int* __restrict__ rowstart, const int* __restrict__ g_bin,
                            const int* __restrict__ bbase, int* __restrict__ perm) {
    __shared__ int cur[256];
    int tid = threadIdx.x, b = blockIdx.x;
    if (tid < 256) cur[tid] = g_bin[tid] + bbase[b * 256 + tid];
    __syncthreads();
    int n = b * 1024 + tid;
    if (n < N_NODES) {
        int deg = rowstart[n + 1] - rowstart[n];
        int pos = atomicAdd(&cur[min(deg, 255)], 1);
        perm[pos] = n;
    }
}

// ---------------- W pre-pack + cursor zeroing ----------------
__global__ void k_wpack(const float* __restrict__ W0, const float* __restrict__ W1,
                        const float* __restrict__ W2, h2v* __restrict__ wpk,
                        int* __restrict__ g_cursor, int* __restrict__ g_bin) {
    int gid = blockIdx.x * 256 + threadIdx.x;  // 3 * 8192
    if (blockIdx.x == 0) {
        if (threadIdx.x < NB2) g_cursor[threadIdx.x] = 0;
        g_bin[threadIdx.x] = 0;
    }
    if (gid >= 3 * 8192) return;
    int L = gid >> 13, r = gid & 8191;
    int k2 = r >> 7, c = r & 127;
    const float* W = (L == 0) ? W0 : ((L == 1) ? W1 : W2);
    h2v v;
    v.x = (_Float16)W[(2 * k2) * HDIM + c];
    v.y = (_Float16)W[(2 * k2 + 1) * HDIM + c];
    wpk[gid] = v;
}

// ---------------- GEMM v3 (fdot2, W from L2): feat(fp16) = act(in) @ W + fused el/er ----------------
__global__ void k_gemm3(const __half* __restrict__ h, const int* __restrict__ xidx,
                        const float* __restrict__ embed, const float4* __restrict__ wpk4,
                        __half* __restrict__ feat_h, const float* __restrict__ bnsc,
                        const float* __restrict__ bnsh, const float* __restrict__ al,
                        const float* __restrict__ ar, float* __restrict__ el,
                        float* __restrict__ er, int mode) {
    __shared__ h2v hsT2[64 * 68];    // [k2][node(+4 pad)] = 17.4 KB
    int tid = threadIdx.x;
    int nbase = blockIdx.x * 64;
    {
        int r = tid & 63, cg = tid >> 6;
        int n = nbase + r;
        bool ok = n < N_NODES;
        h2v vals[16];
#pragma unroll
        for (int j = 0; j < 16; j++) { vals[j].x = (_Float16)0.f; vals[j].y = (_Float16)0.f; }
        if (ok) {
            if (mode == 0) {
                int xi = xidx[n];
                const float4* ep = reinterpret_cast<const float4*>(&embed[xi * HDIM + cg * 32]);
#pragma unroll
                for (int q = 0; q < 8; q++) {
                    float4 e = ep[q];
                    vals[2 * q].x = (_Float16)e.x; vals[2 * q].y = (_Float16)e.y;
                    vals[2 * q + 1].x = (_Float16)e.z; vals[2 * q + 1].y = (_Float16)e.w;
                }
            } else {
                const float4* hp = reinterpret_cast<const float4*>(&h[(size_t)n * HDIM + cg * 32]);
#pragma unroll
                for (int q = 0; q < 4; q++) {
                    float4 raw = hp[q];
                    __half2 us[4] = {*(__half2*)&raw.x, *(__half2*)&raw.y,
                                     *(__half2*)&raw.z, *(__half2*)&raw.w};
#pragma unroll
                    for (int t2 = 0; t2 < 4; t2++) {
                        int j = q * 4 + t2;
                        int c2g = cg * 16 + j;
                        float2 sc = *reinterpret_cast<const float2*>(&bnsc[2 * c2g]);
                        float2 sh = *reinterpret_cast<const float2*>(&bnsh[2 * c2g]);
                        float v0 = __half2float(__low2half(us[t2])) * sc.x + sh.x;
                        float v1 = __half2float(__high2half(us[t2])) * sc.y + sh.y;
                        v0 = (v0 > 0.f) ? v0 : expm1f(v0);
                        v1 = (v1 > 0.f) ? v1 : expm1f(v1);
                        vals[j].x = (_Float16)v0; vals[j].y = (_Float16)v1;
                    }
                }
            }
        }
#pragma unroll
        for (int j = 0; j < 16; j++) hsT2[(cg * 16 + j) * 68 + r] = vals[j];
    }
    __syncthreads();
    int c4 = (tid & 31) * 4;
    int n8 = (tid >> 5) * 8;
    int wlane = tid & 31;
    float acc[8][4] = {};
#pragma unroll 4
    for (int k2 = 0; k2 < 64; k2++) {
        float4 wf = wpk4[k2 * 32 + wlane];   // L2-resident W row chunk
        float4 a0 = *reinterpret_cast<const float4*>(&hsT2[k2 * 68 + n8]);
        float4 a1 = *reinterpret_cast<const float4*>(&hsT2[k2 * 68 + n8 + 4]);
        h2v w[4] = {*(h2v*)&wf.x, *(h2v*)&wf.y, *(h2v*)&wf.z, *(h2v*)&wf.w};
        h2v av[8] = {*(h2v*)&a0.x, *(h2v*)&a0.y, *(h2v*)&a0.z, *(h2v*)&a0.w,
                     *(h2v*)&a1.x, *(h2v*)&a1.y, *(h2v*)&a1.z, *(h2v*)&a1.w};
#pragma unroll
        for (int i = 0; i < 8; i++)
#pragma unroll
            for (int j = 0; j < 4; j++)
                acc[i][j] = __builtin_amdgcn_fdot2(av[i], w[j], acc[i][j], false);
    }
#pragma unroll
    for (int i = 0; i < 8; i++) {
        int n = nbase + n8 + i;
        if (n < N_NODES) {
            __half2* p = reinterpret_cast<__half2*>(&feat_h[(size_t)n * HDIM + c4]);
            p[0] = __floats2half2_rn(acc[i][0], acc[i][1]);
            p[1] = __floats2half2_rn(acc[i][2], acc[i][3]);
        }
    }
    float4 alv = *reinterpret_cast<const float4*>(&al[c4]);
    float4 arv = *reinterpret_cast<const float4*>(&ar[c4]);
    float pl[8], pr[8];
#pragma unroll
    for (int i = 0; i < 8; i++) {
        pl[i] = acc[i][0] * alv.x + acc[i][1] * alv.y + acc[i][2] * alv.z + acc[i][3] * alv.w;
        pr[i] = acc[i][0] * arv.x + acc[i][1] * arv.y + acc[i][2] * arv.z + acc[i][3] * arv.w;
    }
#pragma unroll
    for (int off = 1; off < 8; off <<= 1)
#pragma unroll
        for (int i = 0; i < 8; i++) {
            pl[i] += __shfl_xor(pl[i], off, 64);
            pr[i] += __shfl_xor(pr[i], off, 64);
        }
    int lane = tid & 63;
    if ((lane & 7) == 0) {
        int head = c4 >> 5;
#pragma unroll
        for (int i = 0; i < 8; i++) {
            int n = nbase + n8 + i;
            if (n < N_NODES) {
                el[n * 4 + head] = pl[i];
                er[n * 4 + head] = pr[i];
            }
        }
    }
}

// ---------------- aggregation v8: double-buffered pre-phase + degree-perm ----------------
__global__ void k_agg8(const __half* __restrict__ feat_h, const float* __restrict__ el,
                       const float* __restrict__ er, const int* __restrict__ rowstart,
                       const int* __restrict__ esrc, const float* __restrict__ snorm_n,
                       __half* __restrict__ h, const float* __restrict__ bnsc,
                       const float* __restrict__ bnsh, const int* __restrict__ perm,
                       int layer) {
    __shared__ __align__(16) int2 lds[4][2][2][32][4];  // [wave][h2][buf][slot][head], 16 KB
    int tid = threadIdx.x;
    int wave = tid >> 6, lane = tid & 63;
    int h2 = lane >> 5, hl = lane & 31;
    int dp = hl & 15, epair = hl >> 4, head = dp >> 2;
    int n = perm[blockIdx.x * 8 + wave * 2 + h2];   // degree-sorted assignment
    int e0 = rowstart[n];
    int deg = rowstart[n + 1] - e0;           // >= 1 (self loops)
    int dmax = max(deg, __shfl_xor(deg, 32, 64));
    float4 er4 = *(const float4*)&er[n * 4];
    const float4* fp = reinterpret_cast<const float4*>(feat_h);
    float s = 0.f;
    float a[8] = {};
    int nch = (dmax + 31) >> 5;

    int idx0 = e0 + min(hl, deg - 1);
    int sidx_p = esrc[idx0];
    float4 el_p = *(const float4*)&el[sidx_p * 4];
    bool val_p = hl < deg;

    for (int c = 0; c < nch; c++) {
        float w0 = 0.f, w1 = 0.f, w2 = 0.f, w3 = 0.f;
        int sv = sidx_p;
        if (val_p) {
            float ex = el_p.x + er4.x, ey = el_p.y + er4.y;
            float ez = el_p.z + er4.z, ew = el_p.w + er4.w;
            ex = fmaxf(ex, 0.f) + 0.2f * fminf(ex, 0.f);
            ey = fmaxf(ey, 0.f) + 0.2f * fminf(ey, 0.f);
            ez = fmaxf(ez, 0.f) + 0.2f * fminf(ez, 0.f);
            ew = fmaxf(ew, 0.f) + 0.2f * fminf(ew, 0.f);
            w0 = __expf(ex); w1 = __expf(ey); w2 = __expf(ez); w3 = __expf(ew);
        }
        int4* wp = reinterpret_cast<int4*>(&lds[wave][h2][c & 1][hl][0]);
        wp[0] = make_int4(sv, __float_as_int(w0), sv, __float_as_int(w1));
        wp[1] = make_int4(sv, __float_as_int(w2), sv, __float_as_int(w3));
        if (c + 1 < nch) {
            int slot = (c + 1) * 32 + hl;
            int idx = e0 + min(slot, deg - 1);
            sidx_p = esrc[idx];
            el_p = *(const float4*)&el[sidx_p * 4];
            val_p = slot < deg;
        }
        int cnt = min(32, dmax - c * 32);
        int iters = (cnt + 1) >> 1;
#pragma unroll 4
        for (int j = 0; j < iters; j++) {
            int2 rec = lds[wave][h2][c & 1][j * 2 + epair][head];
            float w = __int_as_float(rec.y);
            float4 fv = fp[(size_t)rec.x * 16 + dp];
            __half2 p0 = *(__half2*)&fv.x, p1 = *(__half2*)&fv.y;
            __half2 p2 = *(__half2*)&fv.z, p3 = *(__half2*)&fv.w;
            a[0] = fmaf(__half2float(__low2half(p0)), w, a[0]);
            a[1] = fmaf(__half2float(__high2half(p0)), w, a[1]);
            a[2] = fmaf(__half2float(__low2half(p1)), w, a[2]);
            a[3] = fmaf(__half2float(__high2half(p1)), w, a[3]);
            a[4] = fmaf(__half2float(__low2half(p2)), w, a[4]);
            a[5] = fmaf(__half2float(__high2half(p2)), w, a[5]);
            a[6] = fmaf(__half2float(__low2half(p3)), w, a[6]);
            a[7] = fmaf(__half2float(__high2half(p3)), w, a[7]);
            s += w;
        }
    }
#pragma unroll
    for (int k = 0; k < 8; k++) a[k] += __shfl_xor(a[k], 16, 64);
    s += __shfl_xor(s, 16, 64);
    if (epair == 0) {
        float inv = 1.f / s;
        int d0 = dp * 8;
        float r[8];
#pragma unroll
        for (int k = 0; k < 8; k++) r[k] = a[k] * inv;
        if (layer > 0) {
            float4 hraw = *reinterpret_cast<const float4*>(&h[(size_t)n * HDIM + d0]);
            __half2 q0 = *(__half2*)&hraw.x, q1 = *(__half2*)&hraw.y;
            __half2 q2 = *(__half2*)&hraw.z, q3 = *(__half2*)&hraw.w;
            float hv[8] = {__half2float(__low2half(q0)), __half2float(__high2half(q0)),
                           __half2float(__low2half(q1)), __half2float(__high2half(q1)),
                           __half2float(__low2half(q2)), __half2float(__high2half(q2)),
                           __half2float(__low2half(q3)), __half2float(__high2half(q3))};
            float4 sc0 = *reinterpret_cast<const float4*>(&bnsc[d0]);
            float4 sc1 = *reinterpret_cast<const float4*>(&bnsc[d0 + 4]);
            float4 sh0 = *reinterpret_cast<const float4*>(&bnsh[d0]);
            float4 sh1 = *reinterpret_cast<const float4*>(&bnsh[d0 + 4]);
            float scv[8] = {sc0.x, sc0.y, sc0.z, sc0.w, sc1.x, sc1.y, sc1.z, sc1.w};
            float shv[8] = {sh0.x, sh0.y, sh0.z, sh0.w, sh1.x, sh1.y, sh1.z, sh1.w};
#pragma unroll
            for (int k = 0; k < 8; k++) {
                float t = hv[k] * scv[k] + shv[k];
                t = (t > 0.f) ? t : expm1f(t);
                r[k] += t;
                r[k] = (r[k] > 0.f) ? r[k] : expm1f(r[k]);
            }
        }
        float sn = snorm_n[n];
#pragma unroll
        for (int k = 0; k < 8; k++) r[k] *= sn;
        float4 outv;
        *(__half2*)&outv.x = __floats2half2_rn(r[0], r[1]);
        *(__half2*)&outv.y = __floats2half2_rn(r[2], r[3]);
        *(__half2*)&outv.z = __floats2half2_rn(r[4], r[5]);
        *(__half2*)&outv.w = __floats2half2_rn(r[6], r[7]);
        *reinterpret_cast<float4*>(&h[(size_t)n * HDIM + d0]) = outv;
    }
}

// ---------------- BatchNorm: deterministic two-level fp32 reduction (h fp16) ----------------
constexpr int BN_NB = 200;
constexpr int BN_ROWS = N_NODES / BN_NB;  // 250

__global__ void k_bn1(const __half* __restrict__ h, float* __restrict__ part) {
    __shared__ float red[8][128][2];
    int tid = threadIdx.x;
    int c = tid & 127, g = tid >> 7;
    int r0 = blockIdx.x * BN_ROWS;
    float s = 0.f, s2 = 0.f;
    for (int r = r0 + g; r < r0 + BN_ROWS; r += 8) {
        float x = __half2float(h[(size_t)r * HDIM + c]);
        s += x;
        s2 = fmaf(x, x, s2);
    }
    red[g][c][0] = s;
    red[g][c][1] = s2;
    __syncthreads();
    if (tid < 128) {
        float ts = 0.f, ts2 = 0.f;
#pragma unroll
        for (int g2 = 0; g2 < 8; g2++) { ts += red[g2][tid][0]; ts2 += red[g2][tid][1]; }
        part[blockIdx.x * 256 + tid] = ts;
        part[blockIdx.x * 256 + 128 + tid] = ts2;
    }
}

__global__ void k_bn2(const float* __restrict__ part, const float* __restrict__ gamma,
                      const float* __restrict__ beta, float* __restrict__ scale,
                      float* __restrict__ shift) {
    int c = threadIdx.x;  // 128
    float s = 0.f, s2 = 0.f;
    for (int b = 0; b < BN_NB; b++) {
        s += part[b * 256 + c];
        s2 += part[b * 256 + 128 + c];
    }
    float mu = s / N_NODES;
    float var = s2 / N_NODES - mu * mu;
    float sc = gamma[c] * rsqrtf(var + 1e-5f);
    scale[c] = sc;
    shift[c] = beta[c] - mu * sc;
}

// ---------------- classifier (h fp16) ----------------
__global__ void k_classifier(const __half* __restrict__ h, const float* __restrict__ W1,
                             const float* __restrict__ b1, const float* __restrict__ W2,
                             const float* __restrict__ b2, const float* __restrict__ bnsc,
                             const float* __restrict__ bnsh, float* __restrict__ out) {
    __shared__ float hs[16][128];
    int tid = threadIdx.x;
    int nbase = blockIdx.x * 16;
    for (int i = tid; i < 16 * 128; i += 256) {
        int r = i >> 7, c = i & 127;
        int n = nbase + r;
        float v = 0.f;
        if (n < N_NODES) {
            v = __half2float(h[(size_t)n * HDIM + c]) * bnsc[c] + bnsh[c];
            v = (v > 0.f) ? v : expm1f(v);
        }
        hs[r][c] = v;
    }
    __syncthreads();
    int j = tid & 63;
    int g = tid >> 6;
    float bj = b1[j];
    float acc[4] = {bj, bj, bj, bj};
    for (int k = 0; k < 128; k++) {
        float w = W1[k * 64 + j];
#pragma unroll
        for (int i = 0; i < 4; i++) acc[i] += hs[g * 4 + i][k] * w;
    }
    float w20 = W2[j * 2], w21 = W2[j * 2 + 1];
    float res[8];
#pragma unroll
    for (int i = 0; i < 4; i++) {
        float hid = fmaxf(acc[i], 0.f);
        res[2 * i] = hid * w20;
        res[2 * i + 1] = hid * w21;
    }
#pragma unroll
    for (int off = 1; off < 64; off <<= 1)
#pragma unroll
        for (int i = 0; i < 8; i++) res[i] += __shfl_xor(res[i], off, 64);
    if (j < 8) {
        int n = nbase + g * 4 + (j >> 1);
        if (n < N_NODES) out[n * 2 + (j & 1)] = res[j] + b2[j & 1];
    }
}

// ----------------------------------------------------------------
extern "C" void kernel_launch(void* const* d_in, const int* in_sizes, int n_in,
                              void* d_out, int out_size, void* d_ws, size_t ws_size,
                              hipStream_t stream) {
    const int* x = (const int*)d_in[0];
    const int* src = (const int*)d_in[1];
    const int* dst = (const int*)d_in[2];
    const float* snorm_n = (const float*)d_in[3];
    const float* embed = (const float*)d_in[5];
    const float* Ws[3] = {(const float*)d_in[6], (const float*)d_in[11], (const float*)d_in[16]};
    const float* als[3] = {(const float*)d_in[7], (const float*)d_in[12], (const float*)d_in[17]};
    const float* ars[3] = {(const float*)d_in[8], (const float*)d_in[13], (const float*)d_in[18]};
    const float* gms[3] = {(const float*)d_in[9], (const float*)d_in[14], (const float*)d_in[19]};
    const float* bts[3] = {(const float*)d_in[10], (const float*)d_in[15], (const float*)d_in[20]};
    const float* cls1_w = (const float*)d_in[21];
    const float* cls1_b = (const float*)d_in[22];
    const float* cls2_w = (const float*)d_in[23];
    const float* cls2_b = (const float*)d_in[24];
    float* out = (float*)d_out;

    char* ws = (char*)d_ws;
    size_t off = 0;
    auto alloc = [&](size_t bytes) {
        void* p = ws + off;
        off = (off + bytes + 255) & ~(size_t)255;
        return p;
    };
    __half* h = (__half*)alloc((size_t)N_NODES * HDIM * 2);
    __half* feat_h = (__half*)alloc((size_t)N_NODES * HDIM * 2);
    float* el = (float*)alloc((size_t)N_NODES * 4 * 4);
    float* er = (float*)alloc((size_t)N_NODES * 4 * 4);
    int* rowstart = (int*)alloc((size_t)(N_NODES + 1) * 4);
    int* esrc = (int*)alloc((size_t)N_EDGES * 4);
    int* perm = (int*)alloc((size_t)N_NODES * 4);
    int* g_cursor = (int*)alloc((size_t)NB2 * 4);
    int* g_bin = (int*)alloc(256 * 4);
    int* bbase = (int*)alloc((size_t)DP_NB * 256 * 4);
    float* bn_part = (float*)alloc((size_t)BN_NB * 256 * 4);
    float* bn_scale = (float*)alloc(128 * 4);
    float* bn_shift = (float*)alloc(128 * 4);
    h2v* wpk = (h2v*)alloc((size_t)3 * 8192 * 4);
    unsigned* g_bucket = (unsigned*)feat_h;  // 4 MB alias; CSR build finishes before gemm
    (void)ws_size; (void)in_sizes; (void)n_in; (void)out_size;

    // wpack also zeroes g_cursor + g_bin (runs before partA in the serial stream)
    k_wpack<<<(3 * 8192 + 255) / 256, 256, 0, stream>>>(Ws[0], Ws[1], Ws[2], wpk,
                                                        g_cursor, g_bin);
    k_partA<<<GA, 1024, 0, stream>>>(src, dst, g_cursor, g_bucket);
    k_partB<<<NB2, 1024, 0, stream>>>(g_bucket, g_cursor, rowstart, esrc);
    k_dhist<<<DP_NB, 1024, 0, stream>>>(rowstart, g_bin, bbase);
    k_dscan<<<1, 64, 0, stream>>>(g_bin);
    k_dscatter2<<<DP_NB, 1024, 0, stream>>>(rowstart, g_bin, bbase, perm);

    for (int L = 0; L < 3; L++) {
        const float4* wpk4 = reinterpret_cast<const float4*>(wpk + (size_t)L * 8192);
        k_gemm3<<<(N_NODES + 63) / 64, 256, 0, stream>>>(h, x, embed, wpk4,
                                                         feat_h, bn_scale, bn_shift,
                                                         als[L], ars[L], el, er, L == 0 ? 0 : 1);
        k_agg8<<<N_NODES / 8, 256, 0, stream>>>(feat_h, el, er, rowstart, esrc,
                                                snorm_n, h, bn_scale, bn_shift, perm, L);
        k_bn1<<<BN_NB, 1024, 0, stream>>>(h, bn_part);
        k_bn2<<<1, 128, 0, stream>>>(bn_part, gms[L], bts[L], bn_scale, bn_shift);
    }

    k_classifier<<<(N_NODES + 15) / 16, 256, 0, stream>>>(h, cls1_w, cls1_b, cls2_w, cls2_b,
                                                          bn_scale, bn_shift, out);
}

// Round 20
// 416.597 us; speedup vs baseline: 1.6918x; 1.0374x over previous
//
#include <hip/hip_runtime.h>
#include <hip/hip_bf16.h>
#include <hip/hip_fp16.h>
#include <math.h>

constexpr int N_NODES = 50000;
constexpr int N_EDGES = 850000;
constexpr int HDIM = 128;   // H*D

typedef _Float16 h2v __attribute__((ext_vector_type(2)));

// ---------------- CSR build: two-phase bucket sort ----------------
constexpr int NB2 = 128;                                // buckets
constexpr int RANGE2 = (N_NODES + NB2 - 1) / NB2;       // 391 nodes/bucket
constexpr int CAP = 8192;                               // bucket capacity (avg 6641)
constexpr int CHUNK = 8192;                             // edges per phase-A block
constexpr int GA = (N_EDGES + CHUNK - 1) / CHUNK;       // 104 blocks

__global__ void k_partA(const int* __restrict__ src, const int* __restrict__ dst,
                        int* __restrict__ g_cursor, unsigned* __restrict__ bucket) {
    __shared__ int hist[NB2];
    int tid = threadIdx.x;
    int e0 = blockIdx.x * CHUNK;
    int e1 = min(e0 + CHUNK, N_EDGES);
    if (tid < NB2) hist[tid] = 0;
    __syncthreads();
    for (int i = e0 + tid; i < e1; i += 1024) {
        int d = dst[i];
        atomicAdd(&hist[d / RANGE2], 1);
    }
    __syncthreads();
    int base = 0;
    if (tid < NB2) base = atomicAdd(&g_cursor[tid], hist[tid]);
    __syncthreads();
    if (tid < NB2) hist[tid] = base;
    __syncthreads();
    for (int i = e0 + tid; i < e1; i += 1024) {
        int d = dst[i];
        int s = src[i];
        int b = d / RANGE2;
        int p = atomicAdd(&hist[b], 1);
        bucket[b * CAP + p] = (unsigned)s | ((unsigned)(d - b * RANGE2) << 16);
    }
}

__global__ void k_partB(const unsigned* __restrict__ bucket, const int* __restrict__ cnts,
                        int* __restrict__ rowstart, int* __restrict__ esrc) {
    __shared__ int cnt_s[NB2];
    __shared__ int hist[RANGE2];
    __shared__ int lcur[RANGE2];
    __shared__ int wsum[7];
    int b = blockIdx.x, tid = threadIdx.x;
    int lo = b * RANGE2;
    int myCount = cnts[b];
    if (tid < NB2) cnt_s[tid] = cnts[tid];
    __syncthreads();
    for (int off = 1; off < NB2; off <<= 1) {
        int t = (tid < NB2 && tid >= off) ? cnt_s[tid - off] : 0;
        __syncthreads();
        if (tid < NB2) cnt_s[tid] += t;
        __syncthreads();
    }
    int base = cnt_s[b] - myCount;
    for (int j = tid; j < RANGE2; j += 1024) hist[j] = 0;
    __syncthreads();
    const unsigned* my = bucket + (size_t)b * CAP;
    for (int i = tid; i < myCount; i += 1024) atomicAdd(&hist[my[i] >> 16], 1);
    __syncthreads();
    int v = 0;
    if (tid < 448) v = (tid < RANGE2) ? hist[tid] : 0;
    int inc = v;
    int lane = tid & 63;
#pragma unroll
    for (int off = 1; off < 64; off <<= 1) {
        int t = __shfl_up(inc, off, 64);
        if (lane >= off) inc += t;
    }
    if (tid < 448 && lane == 63) wsum[tid >> 6] = inc;
    __syncthreads();
    if (tid < RANGE2) {
        int woff = 0;
        for (int w = 0; w < (tid >> 6); w++) woff += wsum[w];
        int excl = woff + inc - v;
        lcur[tid] = excl;
        int node = lo + tid;
        if (node < N_NODES) rowstart[node] = base + excl;
    }
    if (b == 0 && tid == 0) rowstart[N_NODES] = N_EDGES;
    __syncthreads();
    for (int i = tid; i < myCount; i += 1024) {
        unsigned p = my[i];
        int pos = atomicAdd(&lcur[p >> 16], 1);
        esrc[base + pos] = (int)(p & 0xFFFFu);
    }
}

// ---------------- W pre-pack: Wpk[L][k2][c] = half2(W[2k2][c], W[2k2+1][c]) ----------------
__global__ void k_wpack(const float* __restrict__ W0, const float* __restrict__ W1,
                        const float* __restrict__ W2, h2v* __restrict__ wpk) {
    int gid = blockIdx.x * 256 + threadIdx.x;  // 3 * 8192
    if (gid >= 3 * 8192) return;
    int L = gid >> 13, r = gid & 8191;
    int k2 = r >> 7, c = r & 127;
    const float* W = (L == 0) ? W0 : ((L == 1) ? W1 : W2);
    h2v v;
    v.x = (_Float16)W[(2 * k2) * HDIM + c];
    v.y = (_Float16)W[(2 * k2 + 1) * HDIM + c];
    wpk[gid] = v;
}

// ---------------- GEMM v3 (fdot2, W from L2): feat(fp16) = act(in) @ W + fused el/er ----------------
// 64 nodes/block, 256 thr. Only A (17 KB) in LDS -> high occupancy. W streamed from L2:
// per k2 iter, lanes 0-31 read one contiguous 512B Wpk row (lanes 32-63 duplicate -> coalesced).
__global__ void k_gemm3(const __half* __restrict__ h, const int* __restrict__ xidx,
                        const float* __restrict__ embed, const float4* __restrict__ wpk4,
                        __half* __restrict__ feat_h, const float* __restrict__ bnsc,
                        const float* __restrict__ bnsh, const float* __restrict__ al,
                        const float* __restrict__ ar, float* __restrict__ el,
                        float* __restrict__ er, int mode) {
    __shared__ h2v hsT2[64 * 68];    // [k2][node(+4 pad)] = 17.4 KB
    int tid = threadIdx.x;
    int nbase = blockIdx.x * 64;
    // stage A = act(in): thread covers row r = tid&63, cols cg*32..cg*32+31 (cg = tid>>6)
    {
        int r = tid & 63, cg = tid >> 6;
        int n = nbase + r;
        bool ok = n < N_NODES;
        h2v vals[16];
#pragma unroll
        for (int j = 0; j < 16; j++) { vals[j].x = (_Float16)0.f; vals[j].y = (_Float16)0.f; }
        if (ok) {
            if (mode == 0) {
                int xi = xidx[n];
                const float4* ep = reinterpret_cast<const float4*>(&embed[xi * HDIM + cg * 32]);
#pragma unroll
                for (int q = 0; q < 8; q++) {
                    float4 e = ep[q];
                    vals[2 * q].x = (_Float16)e.x; vals[2 * q].y = (_Float16)e.y;
                    vals[2 * q + 1].x = (_Float16)e.z; vals[2 * q + 1].y = (_Float16)e.w;
                }
            } else {
                const float4* hp = reinterpret_cast<const float4*>(&h[(size_t)n * HDIM + cg * 32]);
#pragma unroll
                for (int q = 0; q < 4; q++) {
                    float4 raw = hp[q];
                    __half2 us[4] = {*(__half2*)&raw.x, *(__half2*)&raw.y,
                                     *(__half2*)&raw.z, *(__half2*)&raw.w};
#pragma unroll
                    for (int t2 = 0; t2 < 4; t2++) {
                        int j = q * 4 + t2;
                        int c2g = cg * 16 + j;
                        float2 sc = *reinterpret_cast<const float2*>(&bnsc[2 * c2g]);
                        float2 sh = *reinterpret_cast<const float2*>(&bnsh[2 * c2g]);
                        float v0 = __half2float(__low2half(us[t2])) * sc.x + sh.x;
                        float v1 = __half2float(__high2half(us[t2])) * sc.y + sh.y;
                        v0 = (v0 > 0.f) ? v0 : expm1f(v0);
                        v1 = (v1 > 0.f) ? v1 : expm1f(v1);
                        vals[j].x = (_Float16)v0; vals[j].y = (_Float16)v1;
                    }
                }
            }
        }
#pragma unroll
        for (int j = 0; j < 16; j++) hsT2[(cg * 16 + j) * 68 + r] = vals[j];
    }
    __syncthreads();
    int c4 = (tid & 31) * 4;
    int n8 = (tid >> 5) * 8;
    int wlane = tid & 31;
    float acc[8][4] = {};
#pragma unroll 4
    for (int k2 = 0; k2 < 64; k2++) {
        float4 wf = wpk4[k2 * 32 + wlane];   // L2-resident W row chunk
        float4 a0 = *reinterpret_cast<const float4*>(&hsT2[k2 * 68 + n8]);
        float4 a1 = *reinterpret_cast<const float4*>(&hsT2[k2 * 68 + n8 + 4]);
        h2v w[4] = {*(h2v*)&wf.x, *(h2v*)&wf.y, *(h2v*)&wf.z, *(h2v*)&wf.w};
        h2v av[8] = {*(h2v*)&a0.x, *(h2v*)&a0.y, *(h2v*)&a0.z, *(h2v*)&a0.w,
                     *(h2v*)&a1.x, *(h2v*)&a1.y, *(h2v*)&a1.z, *(h2v*)&a1.w};
#pragma unroll
        for (int i = 0; i < 8; i++)
#pragma unroll
            for (int j = 0; j < 4; j++)
                acc[i][j] = __builtin_amdgcn_fdot2(av[i], w[j], acc[i][j], false);
    }
#pragma unroll
    for (int i = 0; i < 8; i++) {
        int n = nbase + n8 + i;
        if (n < N_NODES) {
            __half2* p = reinterpret_cast<__half2*>(&feat_h[(size_t)n * HDIM + c4]);
            p[0] = __floats2half2_rn(acc[i][0], acc[i][1]);
            p[1] = __floats2half2_rn(acc[i][2], acc[i][3]);
        }
    }
    float4 alv = *reinterpret_cast<const float4*>(&al[c4]);
    float4 arv = *reinterpret_cast<const float4*>(&ar[c4]);
    float pl[8], pr[8];
#pragma unroll
    for (int i = 0; i < 8; i++) {
        pl[i] = acc[i][0] * alv.x + acc[i][1] * alv.y + acc[i][2] * alv.z + acc[i][3] * alv.w;
        pr[i] = acc[i][0] * arv.x + acc[i][1] * arv.y + acc[i][2] * arv.z + acc[i][3] * arv.w;
    }
#pragma unroll
    for (int off = 1; off < 8; off <<= 1)
#pragma unroll
        for (int i = 0; i < 8; i++) {
            pl[i] += __shfl_xor(pl[i], off, 64);
            pr[i] += __shfl_xor(pr[i], off, 64);
        }
    int lane = tid & 63;
    if ((lane & 7) == 0) {
        int head = c4 >> 5;
#pragma unroll
        for (int i = 0; i < 8; i++) {
            int n = nbase + n8 + i;
            if (n < N_NODES) {
                el[n * 4 + head] = pl[i];
                er[n * 4 + head] = pr[i];
            }
        }
    }
}

// ---------------- aggregation v7: double-buffered pre-phase + lean hot loop; h fp16 ----------------
__global__ void k_agg7(const __half* __restrict__ feat_h, const float* __restrict__ el,
                       const float* __restrict__ er, const int* __restrict__ rowstart,
                       const int* __restrict__ esrc, const float* __restrict__ snorm_n,
                       __half* __restrict__ h, const float* __restrict__ bnsc,
                       const float* __restrict__ bnsh, int layer) {
    __shared__ __align__(16) int2 lds[4][2][2][32][4];  // [wave][h2][buf][slot][head], 16 KB
    int tid = threadIdx.x;
    int wave = tid >> 6, lane = tid & 63;
    int h2 = lane >> 5, hl = lane & 31;
    int dp = hl & 15, epair = hl >> 4, head = dp >> 2;
    int n = blockIdx.x * 8 + wave * 2 + h2;   // 6250 blocks * 8 = 50000 exactly
    int e0 = rowstart[n];
    int deg = rowstart[n + 1] - e0;           // >= 1 (self loops)
    int dmax = max(deg, __shfl_xor(deg, 32, 64));
    float4 er4 = *(const float4*)&er[n * 4];
    const float4* fp = reinterpret_cast<const float4*>(feat_h);
    float s = 0.f;
    float a[8] = {};
    int nch = (dmax + 31) >> 5;

    int idx0 = e0 + min(hl, deg - 1);
    int sidx_p = esrc[idx0];
    float4 el_p = *(const float4*)&el[sidx_p * 4];
    bool val_p = hl < deg;

    for (int c = 0; c < nch; c++) {
        float w0 = 0.f, w1 = 0.f, w2 = 0.f, w3 = 0.f;
        int sv = sidx_p;
        if (val_p) {
            float ex = el_p.x + er4.x, ey = el_p.y + er4.y;
            float ez = el_p.z + er4.z, ew = el_p.w + er4.w;
            ex = fmaxf(ex, 0.f) + 0.2f * fminf(ex, 0.f);
            ey = fmaxf(ey, 0.f) + 0.2f * fminf(ey, 0.f);
            ez = fmaxf(ez, 0.f) + 0.2f * fminf(ez, 0.f);
            ew = fmaxf(ew, 0.f) + 0.2f * fminf(ew, 0.f);
            w0 = __expf(ex); w1 = __expf(ey); w2 = __expf(ez); w3 = __expf(ew);
        }
        int4* wp = reinterpret_cast<int4*>(&lds[wave][h2][c & 1][hl][0]);
        wp[0] = make_int4(sv, __float_as_int(w0), sv, __float_as_int(w1));
        wp[1] = make_int4(sv, __float_as_int(w2), sv, __float_as_int(w3));
        if (c + 1 < nch) {
            int slot = (c + 1) * 32 + hl;
            int idx = e0 + min(slot, deg - 1);
            sidx_p = esrc[idx];
            el_p = *(const float4*)&el[sidx_p * 4];
            val_p = slot < deg;
        }
        int cnt = min(32, dmax - c * 32);
        int iters = (cnt + 1) >> 1;
#pragma unroll 2
        for (int j = 0; j < iters; j++) {
            int2 rec = lds[wave][h2][c & 1][j * 2 + epair][head];
            float w = __int_as_float(rec.y);
            float4 fv = fp[(size_t)rec.x * 16 + dp];
            __half2 p0 = *(__half2*)&fv.x, p1 = *(__half2*)&fv.y;
            __half2 p2 = *(__half2*)&fv.z, p3 = *(__half2*)&fv.w;
            a[0] = fmaf(__half2float(__low2half(p0)), w, a[0]);
            a[1] = fmaf(__half2float(__high2half(p0)), w, a[1]);
            a[2] = fmaf(__half2float(__low2half(p1)), w, a[2]);
            a[3] = fmaf(__half2float(__high2half(p1)), w, a[3]);
            a[4] = fmaf(__half2float(__low2half(p2)), w, a[4]);
            a[5] = fmaf(__half2float(__high2half(p2)), w, a[5]);
            a[6] = fmaf(__half2float(__low2half(p3)), w, a[6]);
            a[7] = fmaf(__half2float(__high2half(p3)), w, a[7]);
            s += w;
        }
    }
#pragma unroll
    for (int k = 0; k < 8; k++) a[k] += __shfl_xor(a[k], 16, 64);
    s += __shfl_xor(s, 16, 64);
    if (epair == 0) {
        float inv = 1.f / s;
        int d0 = dp * 8;
        float r[8];
#pragma unroll
        for (int k = 0; k < 8; k++) r[k] = a[k] * inv;
        if (layer > 0) {
            float4 hraw = *reinterpret_cast<const float4*>(&h[(size_t)n * HDIM + d0]);
            __half2 q0 = *(__half2*)&hraw.x, q1 = *(__half2*)&hraw.y;
            __half2 q2 = *(__half2*)&hraw.z, q3 = *(__half2*)&hraw.w;
            float hv[8] = {__half2float(__low2half(q0)), __half2float(__high2half(q0)),
                           __half2float(__low2half(q1)), __half2float(__high2half(q1)),
                           __half2float(__low2half(q2)), __half2float(__high2half(q2)),
                           __half2float(__low2half(q3)), __half2float(__high2half(q3))};
            float4 sc0 = *reinterpret_cast<const float4*>(&bnsc[d0]);
            float4 sc1 = *reinterpret_cast<const float4*>(&bnsc[d0 + 4]);
            float4 sh0 = *reinterpret_cast<const float4*>(&bnsh[d0]);
            float4 sh1 = *reinterpret_cast<const float4*>(&bnsh[d0 + 4]);
            float scv[8] = {sc0.x, sc0.y, sc0.z, sc0.w, sc1.x, sc1.y, sc1.z, sc1.w};
            float shv[8] = {sh0.x, sh0.y, sh0.z, sh0.w, sh1.x, sh1.y, sh1.z, sh1.w};
#pragma unroll
            for (int k = 0; k < 8; k++) {
                float t = hv[k] * scv[k] + shv[k];
                t = (t > 0.f) ? t : expm1f(t);
                r[k] += t;
                r[k] = (r[k] > 0.f) ? r[k] : expm1f(r[k]);
            }
        }
        float sn = snorm_n[n];
#pragma unroll
        for (int k = 0; k < 8; k++) r[k] *= sn;
        float4 outv;
        *(__half2*)&outv.x = __floats2half2_rn(r[0], r[1]);
        *(__half2*)&outv.y = __floats2half2_rn(r[2], r[3]);
        *(__half2*)&outv.z = __floats2half2_rn(r[4], r[5]);
        *(__half2*)&outv.w = __floats2half2_rn(r[6], r[7]);
        *reinterpret_cast<float4*>(&h[(size_t)n * HDIM + d0]) = outv;
    }
}

// ---------------- BatchNorm: deterministic two-level fp32 reduction (h fp16) ----------------
constexpr int BN_NB = 200;
constexpr int BN_ROWS = N_NODES / BN_NB;  // 250

__global__ void k_bn1(const __half* __restrict__ h, float* __restrict__ part) {
    __shared__ float red[8][128][2];
    int tid = threadIdx.x;
    int c = tid & 127, g = tid >> 7;
    int r0 = blockIdx.x * BN_ROWS;
    float s = 0.f, s2 = 0.f;
    for (int r = r0 + g; r < r0 + BN_ROWS; r += 8) {
        float x = __half2float(h[(size_t)r * HDIM + c]);
        s += x;
        s2 = fmaf(x, x, s2);
    }
    red[g][c][0] = s;
    red[g][c][1] = s2;
    __syncthreads();
    if (tid < 128) {
        float ts = 0.f, ts2 = 0.f;
#pragma unroll
        for (int g2 = 0; g2 < 8; g2++) { ts += red[g2][tid][0]; ts2 += red[g2][tid][1]; }
        part[blockIdx.x * 256 + tid] = ts;
        part[blockIdx.x * 256 + 128 + tid] = ts2;
    }
}

__global__ void k_bn2(const float* __restrict__ part, const float* __restrict__ gamma,
                      const float* __restrict__ beta, float* __restrict__ scale,
                      float* __restrict__ shift) {
    int c = threadIdx.x;  // 128
    float s = 0.f, s2 = 0.f;
    for (int b = 0; b < BN_NB; b++) {
        s += part[b * 256 + c];
        s2 += part[b * 256 + 128 + c];
    }
    float mu = s / N_NODES;
    float var = s2 / N_NODES - mu * mu;
    float sc = gamma[c] * rsqrtf(var + 1e-5f);
    scale[c] = sc;
    shift[c] = beta[c] - mu * sc;
}

// ---------------- classifier (h fp16) ----------------
__global__ void k_classifier(const __half* __restrict__ h, const float* __restrict__ W1,
                             const float* __restrict__ b1, const float* __restrict__ W2,
                             const float* __restrict__ b2, const float* __restrict__ bnsc,
                             const float* __restrict__ bnsh, float* __restrict__ out) {
    __shared__ float hs[16][128];
    int tid = threadIdx.x;
    int nbase = blockIdx.x * 16;
    for (int i = tid; i < 16 * 128; i += 256) {
        int r = i >> 7, c = i & 127;
        int n = nbase + r;
        float v = 0.f;
        if (n < N_NODES) {
            v = __half2float(h[(size_t)n * HDIM + c]) * bnsc[c] + bnsh[c];
            v = (v > 0.f) ? v : expm1f(v);
        }
        hs[r][c] = v;
    }
    __syncthreads();
    int j = tid & 63;
    int g = tid >> 6;
    float bj = b1[j];
    float acc[4] = {bj, bj, bj, bj};
    for (int k = 0; k < 128; k++) {
        float w = W1[k * 64 + j];
#pragma unroll
        for (int i = 0; i < 4; i++) acc[i] += hs[g * 4 + i][k] * w;
    }
    float w20 = W2[j * 2], w21 = W2[j * 2 + 1];
    float res[8];
#pragma unroll
    for (int i = 0; i < 4; i++) {
        float hid = fmaxf(acc[i], 0.f);
        res[2 * i] = hid * w20;
        res[2 * i + 1] = hid * w21;
    }
#pragma unroll
    for (int off = 1; off < 64; off <<= 1)
#pragma unroll
        for (int i = 0; i < 8; i++) res[i] += __shfl_xor(res[i], off, 64);
    if (j < 8) {
        int n = nbase + g * 4 + (j >> 1);
        if (n < N_NODES) out[n * 2 + (j & 1)] = res[j] + b2[j & 1];
    }
}

// ----------------------------------------------------------------
extern "C" void kernel_launch(void* const* d_in, const int* in_sizes, int n_in,
                              void* d_out, int out_size, void* d_ws, size_t ws_size,
                              hipStream_t stream) {
    const int* x = (const int*)d_in[0];
    const int* src = (const int*)d_in[1];
    const int* dst = (const int*)d_in[2];
    const float* snorm_n = (const float*)d_in[3];
    const float* embed = (const float*)d_in[5];
    const float* Ws[3] = {(const float*)d_in[6], (const float*)d_in[11], (const float*)d_in[16]};
    const float* als[3] = {(const float*)d_in[7], (const float*)d_in[12], (const float*)d_in[17]};
    const float* ars[3] = {(const float*)d_in[8], (const float*)d_in[13], (const float*)d_in[18]};
    const float* gms[3] = {(const float*)d_in[9], (const float*)d_in[14], (const float*)d_in[19]};
    const float* bts[3] = {(const float*)d_in[10], (const float*)d_in[15], (const float*)d_in[20]};
    const float* cls1_w = (const float*)d_in[21];
    const float* cls1_b = (const float*)d_in[22];
    const float* cls2_w = (const float*)d_in[23];
    const float* cls2_b = (const float*)d_in[24];
    float* out = (float*)d_out;

    char* ws = (char*)d_ws;
    size_t off = 0;
    auto alloc = [&](size_t bytes) {
        void* p = ws + off;
        off = (off + bytes + 255) & ~(size_t)255;
        return p;
    };
    __half* h = (__half*)alloc((size_t)N_NODES * HDIM * 2);
    __half* feat_h = (__half*)alloc((size_t)N_NODES * HDIM * 2);
    float* el = (float*)alloc((size_t)N_NODES * 4 * 4);
    float* er = (float*)alloc((size_t)N_NODES * 4 * 4);
    int* rowstart = (int*)alloc((size_t)(N_NODES + 1) * 4);
    int* esrc = (int*)alloc((size_t)N_EDGES * 4);
    int* g_cursor = (int*)alloc((size_t)NB2 * 4);
    float* bn_part = (float*)alloc((size_t)BN_NB * 256 * 4);
    float* bn_scale = (float*)alloc(128 * 4);
    float* bn_shift = (float*)alloc(128 * 4);
    h2v* wpk = (h2v*)alloc((size_t)3 * 8192 * 4);
    unsigned* g_bucket = (unsigned*)feat_h;  // 4 MB alias; CSR build finishes before gemm
    (void)ws_size; (void)in_sizes; (void)n_in; (void)out_size;

    hipMemsetAsync(g_cursor, 0, NB2 * 4, stream);
    k_wpack<<<(3 * 8192 + 255) / 256, 256, 0, stream>>>(Ws[0], Ws[1], Ws[2], wpk);
    k_partA<<<GA, 1024, 0, stream>>>(src, dst, g_cursor, g_bucket);
    k_partB<<<NB2, 1024, 0, stream>>>(g_bucket, g_cursor, rowstart, esrc);

    for (int L = 0; L < 3; L++) {
        const float4* wpk4 = reinterpret_cast<const float4*>(wpk + (size_t)L * 8192);
        k_gemm3<<<(N_NODES + 63) / 64, 256, 0, stream>>>(h, x, embed, wpk4,
                                                         feat_h, bn_scale, bn_shift,
                                                         als[L], ars[L], el, er, L == 0 ? 0 : 1);
        k_agg7<<<N_NODES / 8, 256, 0, stream>>>(feat_h, el, er, rowstart, esrc,
                                                snorm_n, h, bn_scale, bn_shift, L);
        k_bn1<<<BN_NB, 1024, 0, stream>>>(h, bn_part);
        k_bn2<<<1, 128, 0, stream>>>(bn_part, gms[L], bts[L], bn_scale, bn_shift);
    }

    k_classifier<<<(N_NODES + 15) / 16, 256, 0, stream>>>(h, cls1_w, cls1_b, cls2_w, cls2_b,
                                                          bn_scale, bn_shift, out);
}

// Round 21
// 400.928 us; speedup vs baseline: 1.7580x; 1.0391x over previous
//
#include <hip/hip_runtime.h>
#include <hip/hip_bf16.h>
#include <hip/hip_fp16.h>
#include <math.h>

constexpr int N_NODES = 50000;
constexpr int N_EDGES = 850000;
constexpr int HDIM = 128;   // H*D

typedef _Float16 h2v __attribute__((ext_vector_type(2)));

// ---------------- CSR build: two-phase bucket sort ----------------
constexpr int NB2 = 128;                                // buckets
constexpr int RANGE2 = (N_NODES + NB2 - 1) / NB2;       // 391 nodes/bucket
constexpr int CAP = 8192;                               // bucket capacity (avg 6641)
constexpr int CHUNK = 8192;                             // edges per phase-A block
constexpr int GA = (N_EDGES + CHUNK - 1) / CHUNK;       // 104 blocks

__global__ void k_partA(const int* __restrict__ src, const int* __restrict__ dst,
                        int* __restrict__ g_cursor, unsigned* __restrict__ bucket) {
    __shared__ int hist[NB2];
    int tid = threadIdx.x;
    int e0 = blockIdx.x * CHUNK;
    int e1 = min(e0 + CHUNK, N_EDGES);
    if (tid < NB2) hist[tid] = 0;
    __syncthreads();
    for (int i = e0 + tid; i < e1; i += 1024) {
        int d = dst[i];
        atomicAdd(&hist[d / RANGE2], 1);
    }
    __syncthreads();
    int base = 0;
    if (tid < NB2) base = atomicAdd(&g_cursor[tid], hist[tid]);
    __syncthreads();
    if (tid < NB2) hist[tid] = base;
    __syncthreads();
    for (int i = e0 + tid; i < e1; i += 1024) {
        int d = dst[i];
        int s = src[i];
        int b = d / RANGE2;
        int p = atomicAdd(&hist[b], 1);
        bucket[b * CAP + p] = (unsigned)s | ((unsigned)(d - b * RANGE2) << 16);
    }
}

__global__ void k_partB(const unsigned* __restrict__ bucket, const int* __restrict__ cnts,
                        int* __restrict__ rowstart, int* __restrict__ esrc) {
    __shared__ int cnt_s[NB2];
    __shared__ int hist[RANGE2];
    __shared__ int lcur[RANGE2];
    __shared__ int wsum[7];
    int b = blockIdx.x, tid = threadIdx.x;
    int lo = b * RANGE2;
    int myCount = cnts[b];
    if (tid < NB2) cnt_s[tid] = cnts[tid];
    __syncthreads();
    for (int off = 1; off < NB2; off <<= 1) {
        int t = (tid < NB2 && tid >= off) ? cnt_s[tid - off] : 0;
        __syncthreads();
        if (tid < NB2) cnt_s[tid] += t;
        __syncthreads();
    }
    int base = cnt_s[b] - myCount;
    for (int j = tid; j < RANGE2; j += 1024) hist[j] = 0;
    __syncthreads();
    const unsigned* my = bucket + (size_t)b * CAP;
    for (int i = tid; i < myCount; i += 1024) atomicAdd(&hist[my[i] >> 16], 1);
    __syncthreads();
    int v = 0;
    if (tid < 448) v = (tid < RANGE2) ? hist[tid] : 0;
    int inc = v;
    int lane = tid & 63;
#pragma unroll
    for (int off = 1; off < 64; off <<= 1) {
        int t = __shfl_up(inc, off, 64);
        if (lane >= off) inc += t;
    }
    if (tid < 448 && lane == 63) wsum[tid >> 6] = inc;
    __syncthreads();
    if (tid < RANGE2) {
        int woff = 0;
        for (int w = 0; w < (tid >> 6); w++) woff += wsum[w];
        int excl = woff + inc - v;
        lcur[tid] = excl;
        int node = lo + tid;
        if (node < N_NODES) rowstart[node] = base + excl;
    }
    if (b == 0 && tid == 0) rowstart[N_NODES] = N_EDGES;
    __syncthreads();
    for (int i = tid; i < myCount; i += 1024) {
        unsigned p = my[i];
        int pos = atomicAdd(&lcur[p >> 16], 1);
        esrc[base + pos] = (int)(p & 0xFFFFu);
    }
}

// ---------------- W pre-pack: Wpk[L][k2][c] = half2(W[2k2][c], W[2k2+1][c]) ----------------
__global__ void k_wpack(const float* __restrict__ W0, const float* __restrict__ W1,
                        const float* __restrict__ W2, h2v* __restrict__ wpk) {
    int gid = blockIdx.x * 256 + threadIdx.x;  // 3 * 8192
    if (gid >= 3 * 8192) return;
    int L = gid >> 13, r = gid & 8191;
    int k2 = r >> 7, c = r & 127;
    const float* W = (L == 0) ? W0 : ((L == 1) ? W1 : W2);
    h2v v;
    v.x = (_Float16)W[(2 * k2) * HDIM + c];
    v.y = (_Float16)W[(2 * k2 + 1) * HDIM + c];
    wpk[gid] = v;
}

// ---------------- GEMM v4 (fdot2, W from L2, 32-node blocks): feat = act(in)@W + el/er ----------------
// 32 nodes/block, 256 thr, 1563 blocks (~6 blocks/CU). A (9.2 KB) in LDS; W streamed from L2.
// Thread computes 4 nodes x 4 cols; inner loop: 1 L2 float4 + 1 ds_read_b128 + 16 fdot2.
__global__ void k_gemm4(const __half* __restrict__ h, const int* __restrict__ xidx,
                        const float* __restrict__ embed, const float4* __restrict__ wpk4,
                        __half* __restrict__ feat_h, const float* __restrict__ bnsc,
                        const float* __restrict__ bnsh, const float* __restrict__ al,
                        const float* __restrict__ ar, float* __restrict__ el,
                        float* __restrict__ er, int mode) {
    __shared__ h2v hsT2[64 * 36];    // [k2][node(+4 pad)] = 9.2 KB
    int tid = threadIdx.x;
    int nbase = blockIdx.x * 32;
    // stage A = act(in): thread covers row r = tid&31, cols cg*16..cg*16+15 (cg = tid>>5)
    {
        int r = tid & 31, cg = tid >> 5;
        int n = nbase + r;
        bool ok = n < N_NODES;
        h2v vals[8];
#pragma unroll
        for (int j = 0; j < 8; j++) { vals[j].x = (_Float16)0.f; vals[j].y = (_Float16)0.f; }
        if (ok) {
            if (mode == 0) {
                int xi = xidx[n];
                const float4* ep = reinterpret_cast<const float4*>(&embed[xi * HDIM + cg * 16]);
#pragma unroll
                for (int q = 0; q < 4; q++) {
                    float4 e = ep[q];
                    vals[2 * q].x = (_Float16)e.x; vals[2 * q].y = (_Float16)e.y;
                    vals[2 * q + 1].x = (_Float16)e.z; vals[2 * q + 1].y = (_Float16)e.w;
                }
            } else {
                const float4* hp = reinterpret_cast<const float4*>(&h[(size_t)n * HDIM + cg * 16]);
#pragma unroll
                for (int q = 0; q < 2; q++) {
                    float4 raw = hp[q];
                    __half2 us[4] = {*(__half2*)&raw.x, *(__half2*)&raw.y,
                                     *(__half2*)&raw.z, *(__half2*)&raw.w};
#pragma unroll
                    for (int t2 = 0; t2 < 4; t2++) {
                        int j = q * 4 + t2;
                        int c2g = cg * 8 + j;
                        float2 sc = *reinterpret_cast<const float2*>(&bnsc[2 * c2g]);
                        float2 sh = *reinterpret_cast<const float2*>(&bnsh[2 * c2g]);
                        float v0 = __half2float(__low2half(us[t2])) * sc.x + sh.x;
                        float v1 = __half2float(__high2half(us[t2])) * sc.y + sh.y;
                        v0 = (v0 > 0.f) ? v0 : expm1f(v0);
                        v1 = (v1 > 0.f) ? v1 : expm1f(v1);
                        vals[j].x = (_Float16)v0; vals[j].y = (_Float16)v1;
                    }
                }
            }
        }
#pragma unroll
        for (int j = 0; j < 8; j++) hsT2[(cg * 8 + j) * 36 + r] = vals[j];
    }
    __syncthreads();
    int c4 = (tid & 31) * 4;        // 4 cols, within one head
    int n4 = (tid >> 5) * 4;        // 4 nodes
    int wlane = tid & 31;
    float acc[4][4] = {};
#pragma unroll 4
    for (int k2 = 0; k2 < 64; k2++) {
        float4 wf = wpk4[k2 * 32 + wlane];   // L2-resident W row chunk
        float4 a0 = *reinterpret_cast<const float4*>(&hsT2[k2 * 36 + n4]);
        h2v w[4] = {*(h2v*)&wf.x, *(h2v*)&wf.y, *(h2v*)&wf.z, *(h2v*)&wf.w};
        h2v av[4] = {*(h2v*)&a0.x, *(h2v*)&a0.y, *(h2v*)&a0.z, *(h2v*)&a0.w};
#pragma unroll
        for (int i = 0; i < 4; i++)
#pragma unroll
            for (int j = 0; j < 4; j++)
                acc[i][j] = __builtin_amdgcn_fdot2(av[i], w[j], acc[i][j], false);
    }
    // feat stores (fp16)
#pragma unroll
    for (int i = 0; i < 4; i++) {
        int n = nbase + n4 + i;
        if (n < N_NODES) {
            __half2* p = reinterpret_cast<__half2*>(&feat_h[(size_t)n * HDIM + c4]);
            p[0] = __floats2half2_rn(acc[i][0], acc[i][1]);
            p[1] = __floats2half2_rn(acc[i][2], acc[i][3]);
        }
    }
    // fused el/er: reduce over the 8 lanes sharing (node group, head)
    float4 alv = *reinterpret_cast<const float4*>(&al[c4]);
    float4 arv = *reinterpret_cast<const float4*>(&ar[c4]);
    float pl[4], pr[4];
#pragma unroll
    for (int i = 0; i < 4; i++) {
        pl[i] = acc[i][0] * alv.x + acc[i][1] * alv.y + acc[i][2] * alv.z + acc[i][3] * alv.w;
        pr[i] = acc[i][0] * arv.x + acc[i][1] * arv.y + acc[i][2] * arv.z + acc[i][3] * arv.w;
    }
#pragma unroll
    for (int off = 1; off < 8; off <<= 1)
#pragma unroll
        for (int i = 0; i < 4; i++) {
            pl[i] += __shfl_xor(pl[i], off, 64);
            pr[i] += __shfl_xor(pr[i], off, 64);
        }
    int lane = tid & 63;
    if ((lane & 7) == 0) {
        int head = c4 >> 5;
#pragma unroll
        for (int i = 0; i < 4; i++) {
            int n = nbase + n4 + i;
            if (n < N_NODES) {
                el[n * 4 + head] = pl[i];
                er[n * 4 + head] = pr[i];
            }
        }
    }
}

// ---------------- aggregation v7: double-buffered pre-phase + lean hot loop; h fp16 ----------------
__global__ void k_agg7(const __half* __restrict__ feat_h, const float* __restrict__ el,
                       const float* __restrict__ er, const int* __restrict__ rowstart,
                       const int* __restrict__ esrc, const float* __restrict__ snorm_n,
                       __half* __restrict__ h, const float* __restrict__ bnsc,
                       const float* __restrict__ bnsh, int layer) {
    __shared__ __align__(16) int2 lds[4][2][2][32][4];  // [wave][h2][buf][slot][head], 16 KB
    int tid = threadIdx.x;
    int wave = tid >> 6, lane = tid & 63;
    int h2 = lane >> 5, hl = lane & 31;
    int dp = hl & 15, epair = hl >> 4, head = dp >> 2;
    int n = blockIdx.x * 8 + wave * 2 + h2;   // 6250 blocks * 8 = 50000 exactly
    int e0 = rowstart[n];
    int deg = rowstart[n + 1] - e0;           // >= 1 (self loops)
    int dmax = max(deg, __shfl_xor(deg, 32, 64));
    float4 er4 = *(const float4*)&er[n * 4];
    const float4* fp = reinterpret_cast<const float4*>(feat_h);
    float s = 0.f;
    float a[8] = {};
    int nch = (dmax + 31) >> 5;

    int idx0 = e0 + min(hl, deg - 1);
    int sidx_p = esrc[idx0];
    float4 el_p = *(const float4*)&el[sidx_p * 4];
    bool val_p = hl < deg;

    for (int c = 0; c < nch; c++) {
        float w0 = 0.f, w1 = 0.f, w2 = 0.f, w3 = 0.f;
        int sv = sidx_p;
        if (val_p) {
            float ex = el_p.x + er4.x, ey = el_p.y + er4.y;
            float ez = el_p.z + er4.z, ew = el_p.w + er4.w;
            ex = fmaxf(ex, 0.f) + 0.2f * fminf(ex, 0.f);
            ey = fmaxf(ey, 0.f) + 0.2f * fminf(ey, 0.f);
            ez = fmaxf(ez, 0.f) + 0.2f * fminf(ez, 0.f);
            ew = fmaxf(ew, 0.f) + 0.2f * fminf(ew, 0.f);
            w0 = __expf(ex); w1 = __expf(ey); w2 = __expf(ez); w3 = __expf(ew);
        }
        int4* wp = reinterpret_cast<int4*>(&lds[wave][h2][c & 1][hl][0]);
        wp[0] = make_int4(sv, __float_as_int(w0), sv, __float_as_int(w1));
        wp[1] = make_int4(sv, __float_as_int(w2), sv, __float_as_int(w3));
        if (c + 1 < nch) {
            int slot = (c + 1) * 32 + hl;
            int idx = e0 + min(slot, deg - 1);
            sidx_p = esrc[idx];
            el_p = *(const float4*)&el[sidx_p * 4];
            val_p = slot < deg;
        }
        int cnt = min(32, dmax - c * 32);
        int iters = (cnt + 1) >> 1;
#pragma unroll 2
        for (int j = 0; j < iters; j++) {
            int2 rec = lds[wave][h2][c & 1][j * 2 + epair][head];
            float w = __int_as_float(rec.y);
            float4 fv = fp[(size_t)rec.x * 16 + dp];
            __half2 p0 = *(__half2*)&fv.x, p1 = *(__half2*)&fv.y;
            __half2 p2 = *(__half2*)&fv.z, p3 = *(__half2*)&fv.w;
            a[0] = fmaf(__half2float(__low2half(p0)), w, a[0]);
            a[1] = fmaf(__half2float(__high2half(p0)), w, a[1]);
            a[2] = fmaf(__half2float(__low2half(p1)), w, a[2]);
            a[3] = fmaf(__half2float(__high2half(p1)), w, a[3]);
            a[4] = fmaf(__half2float(__low2half(p2)), w, a[4]);
            a[5] = fmaf(__half2float(__high2half(p2)), w, a[5]);
            a[6] = fmaf(__half2float(__low2half(p3)), w, a[6]);
            a[7] = fmaf(__half2float(__high2half(p3)), w, a[7]);
            s += w;
        }
    }
#pragma unroll
    for (int k = 0; k < 8; k++) a[k] += __shfl_xor(a[k], 16, 64);
    s += __shfl_xor(s, 16, 64);
    if (epair == 0) {
        float inv = 1.f / s;
        int d0 = dp * 8;
        float r[8];
#pragma unroll
        for (int k = 0; k < 8; k++) r[k] = a[k] * inv;
        if (layer > 0) {
            float4 hraw = *reinterpret_cast<const float4*>(&h[(size_t)n * HDIM + d0]);
            __half2 q0 = *(__half2*)&hraw.x, q1 = *(__half2*)&hraw.y;
            __half2 q2 = *(__half2*)&hraw.z, q3 = *(__half2*)&hraw.w;
            float hv[8] = {__half2float(__low2half(q0)), __half2float(__high2half(q0)),
                           __half2float(__low2half(q1)), __half2float(__high2half(q1)),
                           __half2float(__low2half(q2)), __half2float(__high2half(q2)),
                           __half2float(__low2half(q3)), __half2float(__high2half(q3))};
            float4 sc0 = *reinterpret_cast<const float4*>(&bnsc[d0]);
            float4 sc1 = *reinterpret_cast<const float4*>(&bnsc[d0 + 4]);
            float4 sh0 = *reinterpret_cast<const float4*>(&bnsh[d0]);
            float4 sh1 = *reinterpret_cast<const float4*>(&bnsh[d0 + 4]);
            float scv[8] = {sc0.x, sc0.y, sc0.z, sc0.w, sc1.x, sc1.y, sc1.z, sc1.w};
            float shv[8] = {sh0.x, sh0.y, sh0.z, sh0.w, sh1.x, sh1.y, sh1.z, sh1.w};
#pragma unroll
            for (int k = 0; k < 8; k++) {
                float t = hv[k] * scv[k] + shv[k];
                t = (t > 0.f) ? t : expm1f(t);
                r[k] += t;
                r[k] = (r[k] > 0.f) ? r[k] : expm1f(r[k]);
            }
        }
        float sn = snorm_n[n];
#pragma unroll
        for (int k = 0; k < 8; k++) r[k] *= sn;
        float4 outv;
        *(__half2*)&outv.x = __floats2half2_rn(r[0], r[1]);
        *(__half2*)&outv.y = __floats2half2_rn(r[2], r[3]);
        *(__half2*)&outv.z = __floats2half2_rn(r[4], r[5]);
        *(__half2*)&outv.w = __floats2half2_rn(r[6], r[7]);
        *reinterpret_cast<float4*>(&h[(size_t)n * HDIM + d0]) = outv;
    }
}

// ---------------- BatchNorm: deterministic two-level fp32 reduction (h fp16) ----------------
constexpr int BN_NB = 200;
constexpr int BN_ROWS = N_NODES / BN_NB;  // 250

__global__ void k_bn1(const __half* __restrict__ h, float* __restrict__ part) {
    __shared__ float red[8][128][2];
    int tid = threadIdx.x;
    int c = tid & 127, g = tid >> 7;
    int r0 = blockIdx.x * BN_ROWS;
    float s = 0.f, s2 = 0.f;
    for (int r = r0 + g; r < r0 + BN_ROWS; r += 8) {
        float x = __half2float(h[(size_t)r * HDIM + c]);
        s += x;
        s2 = fmaf(x, x, s2);
    }
    red[g][c][0] = s;
    red[g][c][1] = s2;
    __syncthreads();
    if (tid < 128) {
        float ts = 0.f, ts2 = 0.f;
#pragma unroll
        for (int g2 = 0; g2 < 8; g2++) { ts += red[g2][tid][0]; ts2 += red[g2][tid][1]; }
        part[blockIdx.x * 256 + tid] = ts;
        part[blockIdx.x * 256 + 128 + tid] = ts2;
    }
}

__global__ void k_bn2(const float* __restrict__ part, const float* __restrict__ gamma,
                      const float* __restrict__ beta, float* __restrict__ scale,
                      float* __restrict__ shift) {
    int c = threadIdx.x;  // 128
    float s = 0.f, s2 = 0.f;
    for (int b = 0; b < BN_NB; b++) {
        s += part[b * 256 + c];
        s2 += part[b * 256 + 128 + c];
    }
    float mu = s / N_NODES;
    float var = s2 / N_NODES - mu * mu;
    float sc = gamma[c] * rsqrtf(var + 1e-5f);
    scale[c] = sc;
    shift[c] = beta[c] - mu * sc;
}

// ---------------- classifier (h fp16) ----------------
__global__ void k_classifier(const __half* __restrict__ h, const float* __restrict__ W1,
                             const float* __restrict__ b1, const float* __restrict__ W2,
                             const float* __restrict__ b2, const float* __restrict__ bnsc,
                             const float* __restrict__ bnsh, float* __restrict__ out) {
    __shared__ float hs[16][128];
    int tid = threadIdx.x;
    int nbase = blockIdx.x * 16;
    for (int i = tid; i < 16 * 128; i += 256) {
        int r = i >> 7, c = i & 127;
        int n = nbase + r;
        float v = 0.f;
        if (n < N_NODES) {
            v = __half2float(h[(size_t)n * HDIM + c]) * bnsc[c] + bnsh[c];
            v = (v > 0.f) ? v : expm1f(v);
        }
        hs[r][c] = v;
    }
    __syncthreads();
    int j = tid & 63;
    int g = tid >> 6;
    float bj = b1[j];
    float acc[4] = {bj, bj, bj, bj};
    for (int k = 0; k < 128; k++) {
        float w = W1[k * 64 + j];
#pragma unroll
        for (int i = 0; i < 4; i++) acc[i] += hs[g * 4 + i][k] * w;
    }
    float w20 = W2[j * 2], w21 = W2[j * 2 + 1];
    float res[8];
#pragma unroll
    for (int i = 0; i < 4; i++) {
        float hid = fmaxf(acc[i], 0.f);
        res[2 * i] = hid * w20;
        res[2 * i + 1] = hid * w21;
    }
#pragma unroll
    for (int off = 1; off < 64; off <<= 1)
#pragma unroll
        for (int i = 0; i < 8; i++) res[i] += __shfl_xor(res[i], off, 64);
    if (j < 8) {
        int n = nbase + g * 4 + (j >> 1);
        if (n < N_NODES) out[n * 2 + (j & 1)] = res[j] + b2[j & 1];
    }
}

// ----------------------------------------------------------------
extern "C" void kernel_launch(void* const* d_in, const int* in_sizes, int n_in,
                              void* d_out, int out_size, void* d_ws, size_t ws_size,
                              hipStream_t stream) {
    const int* x = (const int*)d_in[0];
    const int* src = (const int*)d_in[1];
    const int* dst = (const int*)d_in[2];
    const float* snorm_n = (const float*)d_in[3];
    const float* embed = (const float*)d_in[5];
    const float* Ws[3] = {(const float*)d_in[6], (const float*)d_in[11], (const float*)d_in[16]};
    const float* als[3] = {(const float*)d_in[7], (const float*)d_in[12], (const float*)d_in[17]};
    const float* ars[3] = {(const float*)d_in[8], (const float*)d_in[13], (const float*)d_in[18]};
    const float* gms[3] = {(const float*)d_in[9], (const float*)d_in[14], (const float*)d_in[19]};
    const float* bts[3] = {(const float*)d_in[10], (const float*)d_in[15], (const float*)d_in[20]};
    const float* cls1_w = (const float*)d_in[21];
    const float* cls1_b = (const float*)d_in[22];
    const float* cls2_w = (const float*)d_in[23];
    const float* cls2_b = (const float*)d_in[24];
    float* out = (float*)d_out;

    char* ws = (char*)d_ws;
    size_t off = 0;
    auto alloc = [&](size_t bytes) {
        void* p = ws + off;
        off = (off + bytes + 255) & ~(size_t)255;
        return p;
    };
    __half* h = (__half*)alloc((size_t)N_NODES * HDIM * 2);
    __half* feat_h = (__half*)alloc((size_t)N_NODES * HDIM * 2);
    float* el = (float*)alloc((size_t)N_NODES * 4 * 4);
    float* er = (float*)alloc((size_t)N_NODES * 4 * 4);
    int* rowstart = (int*)alloc((size_t)(N_NODES + 1) * 4);
    int* esrc = (int*)alloc((size_t)N_EDGES * 4);
    int* g_cursor = (int*)alloc((size_t)NB2 * 4);
    float* bn_part = (float*)alloc((size_t)BN_NB * 256 * 4);
    float* bn_scale = (float*)alloc(128 * 4);
    float* bn_shift = (float*)alloc(128 * 4);
    h2v* wpk = (h2v*)alloc((size_t)3 * 8192 * 4);
    unsigned* g_bucket = (unsigned*)feat_h;  // 4 MB alias; CSR build finishes before gemm
    (void)ws_size; (void)in_sizes; (void)n_in; (void)out_size;

    hipMemsetAsync(g_cursor, 0, NB2 * 4, stream);
    k_wpack<<<(3 * 8192 + 255) / 256, 256, 0, stream>>>(Ws[0], Ws[1], Ws[2], wpk);
    k_partA<<<GA, 1024, 0, stream>>>(src, dst, g_cursor, g_bucket);
    k_partB<<<NB2, 1024, 0, stream>>>(g_bucket, g_cursor, rowstart, esrc);

    for (int L = 0; L < 3; L++) {
        const float4* wpk4 = reinterpret_cast<const float4*>(wpk + (size_t)L * 8192);
        k_gemm4<<<(N_NODES + 31) / 32, 256, 0, stream>>>(h, x, embed, wpk4,
                                                         feat_h, bn_scale, bn_shift,
                                                         als[L], ars[L], el, er, L == 0 ? 0 : 1);
        k_agg7<<<N_NODES / 8, 256, 0, stream>>>(feat_h, el, er, rowstart, esrc,
                                                snorm_n, h, bn_scale, bn_shift, L);
        k_bn1<<<BN_NB, 1024, 0, stream>>>(h, bn_part);
        k_bn2<<<1, 128, 0, stream>>>(bn_part, gms[L], bts[L], bn_scale, bn_shift);
    }

    k_classifier<<<(N_NODES + 15) / 16, 256, 0, stream>>>(h, cls1_w, cls1_b, cls2_w, cls2_b,
                                                          bn_scale, bn_shift, out);
}